// Round 8
// baseline (2077.428 us; speedup 1.0000x reference)
//
#include <hip/hip_runtime.h>
#include <stdint.h>

#define T_STEPS 256
#define EMBD 10
#define NKIT 9          // K = 288 = 9*32 (256 h + 10 x + 1 bias + pad)
#define NBLK_K1 (64 * NKIT)
#define NBLK 256        // main grid: 4 hcol-quarters x 64 batch-groups

typedef __attribute__((ext_vector_type(8))) short bf16x8;
typedef __attribute__((ext_vector_type(4))) float f32x4;
typedef __attribute__((ext_vector_type(4))) int   i32x4;

__device__ __forceinline__ unsigned short f2bf(float f) {
    union { float f; unsigned int u; } v; v.f = f;
    unsigned int u = v.u;
    unsigned int r = (u + 0x7FFFu + ((u >> 16) & 1u)) >> 16;  // RNE
    return (unsigned short)r;
}
// R19-proven fast transcendentals (1-ulp): invisible under bf16 h-storage.
__device__ __forceinline__ float sig_fast(float x) {
    return __builtin_amdgcn_rcpf(1.0f + __builtin_amdgcn_exp2f(-1.4426950408889634f * x));
}
__device__ __forceinline__ float tanh_fast(float x) {
    return 1.0f - 2.0f * __builtin_amdgcn_rcpf(__builtin_amdgcn_exp2f(2.8853900817779268f * x) + 1.0f);
}
__device__ __forceinline__ f32x4 mfma_v(i32x4 a, i32x4 b, f32x4 c) {
    return __builtin_amdgcn_mfma_f32_16x16x32_bf16(
        __builtin_bit_cast(bf16x8, a), __builtin_bit_cast(bf16x8, b), c, 0, 0, 0);
}

// ---------------------------------------------------------------------------
// K1: swizzled bf16 weights Wfull[288][1024] in MFMA B-frag order
// [kit 0..8][ntile 0..63][lane] x 16B. Block 0 zeroes ALL flag slots
// (R23's hang: the old tid<128 guard was vacuous on a 64-thread block ->
// parity-1 flags held leftover-garbage negatives -> infinite spin).
// ---------------------------------------------------------------------------
__global__ __launch_bounds__(64) void build_wswz(
    const float* __restrict__ Wgx, const float* __restrict__ Wgh, const float* __restrict__ bg,
    const float* __restrict__ Wix, const float* __restrict__ Wih, const float* __restrict__ bi,
    const float* __restrict__ Wfx, const float* __restrict__ Wfh, const float* __restrict__ bf_,
    const float* __restrict__ Wox, const float* __restrict__ Woh, const float* __restrict__ bo,
    unsigned short* __restrict__ wswz, unsigned int* __restrict__ flags)
{
    if (blockIdx.x == 0) {
#pragma unroll
        for (int j = 0; j < 4; j++)
            flags[threadIdx.x + 64 * j] = 0u;
    }

    int g   = blockIdx.x / NKIT;   // ntile
    int kit = blockIdx.x % NKIT;
    int lane = threadIdx.x;
    int n = g * 16 + (lane & 15);
    int q = n >> 8;
    int col = n & 255;
    const float* Wh = (q == 0) ? Wgh : (q == 1) ? Wih : (q == 2) ? Wfh : Woh;
    const float* Wx = (q == 0) ? Wgx : (q == 1) ? Wix : (q == 2) ? Wfx : Wox;
    const float* bb = (q == 0) ? bg  : (q == 1) ? bi  : (q == 2) ? bf_ : bo;
    int k0 = kit * 32 + (lane >> 4) * 8;

    int4 out;
    unsigned short* p = (unsigned short*)&out;
#pragma unroll
    for (int jx = 0; jx < 8; jx++) {
        int k = k0 + jx;
        float v = 0.0f;
        if (k < 256)             v = Wh[k * 256 + col];
        else if (k < 256 + EMBD) v = Wx[(k - 256) * 256 + col];
        else if (k == 266)       v = bb[col];
        p[jx] = f2bf(v);
    }
    ((int4*)wswz)[(kit * 64 + g) * 64 + lane] = out;
}

// ---------------------------------------------------------------------------
// K2: N-SPLIT persistent LSTM. 256 blocks x 512 threads (8 waves), 1/CU.
// blk = hg*64 + gb: gb = batch group (rows gb*16..+16), hg = hcol quarter.
// Per wave: gate = w&3, 2 local ntiles -> 18 MFMAs/step. B: 7 kits in 56
// regs, kits {5,6} in 32 KB LDS. No AGPR parking, no unparks, no lands.
// h-exchange per step among 4 siblings via hxc + per-(parity,group)
// arrival counters:
//   producer: plain h stores -> __syncthreads (vmcnt drain) ->
//             fetch_add(RELEASE, AGENT)
//   consumer: tid0 BOUNDED spin load(ACQUIRE, AGENT) -> __syncthreads ->
//             plain A-frag loads
// R25: spin is BOUNDED (200k sleeps, wrap-safe compare). If the sync
// reasoning is wrong anywhere, the kernel finishes with wrong output +
// counters instead of hanging the container (R23 burned a round on a
// hang; R24's container died twice with zero data). Bound never fires
// on the correct path.
// WAR ordering (audited): write(t, parity q) is gated behind 4 posts of
// parity p, each issued only after that sibling's parity-q reads at t-1
// completed (B2 drain precedes post). Deadlock-free capacity: <=128 VGPR
// (launch_bounds(512,4)) + ~52 KB LDS => 2 blocks/CU, grid = 1/CU.
// ---------------------------------------------------------------------------
__global__ __launch_bounds__(512, 4)
void lstm_main(
    const int*   __restrict__ xtok,   // [1024][1][256]
    const float* __restrict__ emb,    // [32000][10]
    const float* __restrict__ Wph,    // [256][10]
    const float* __restrict__ bp,     // [10]
    const unsigned short* __restrict__ wswz,
    unsigned int* __restrict__ flags, // [2][64]
    unsigned int* __restrict__ hxc,   // [2][64][16][128] u32 (2 bf16 each)
    float* __restrict__ out)          // [1024][10]
{
    __shared__ __align__(16) unsigned short A8_lds[2][64 * 8];  // 2 KB (kit 8: x+bias)
    __shared__ __align__(16) i32x4 B_lds[2 * 16 * 64];          // 32 KB (kits 5,6)
    __shared__ float z_lds[4 * 16 * 66];                        // 16.5 KB (padded 66)
    __shared__ float outacc[160];

    const int tid  = threadIdx.x;
    const int w    = tid >> 6;        // wave 0..7
    const int lane = tid & 63;
    const int blk  = blockIdx.x;
    const int gb   = blk & 63;        // batch group
    const int hg   = blk >> 6;        // hcol quarter 0..3

    const int gate = w & 3;
    const int ntl0 = (w >> 2) * 2;    // local h-ntile pair base (0 or 2)

    const int m_x = tid >> 4;         // x-gather row (tid<256)
    const int e_x = tid & 15;

    const int r_gm = tid >> 5;        // gate-math row 0..15
    const int hc0  = (tid * 2) & 63;  // gate-math col pair base (even)

    const i32x4* Bg = (const i32x4*)wswz;

    // --- B prologue: regs for kits {0,1,2,3,4,7,8} (56 VGPRs) ---
    i32x4 breg[7][2];
    {
        const int ks[7] = {0, 1, 2, 3, 4, 7, 8};
#pragma unroll
        for (int i = 0; i < 7; i++)
#pragma unroll
            for (int jj = 0; jj < 2; jj++) {
                int ntile = gate * 16 + hg * 4 + ntl0 + jj;
                breg[i][jj] = Bg[(ks[i] * 64 + ntile) * 64 + lane];
            }
    }
    // --- B LDS: kits 5,6 for this block's 16 ntiles ---
    for (int i = tid; i < 2 * 16 * 64; i += 512) {
        int k   = i >> 10;          // 0->kit5, 1->kit6
        int ntl = (i >> 6) & 15;    // local ntile = gt*4 + j
        int ln  = i & 63;
        int gt = ntl >> 2, j = ntl & 3;
        B_lds[i] = Bg[((5 + k) * 64 + gt * 16 + hg * 4 + j) * 64 + ln];
    }

    // --- A8 init: zeros, bias (both parities), x_0 (parity 0) ---
    {
        int4 z4 = {0, 0, 0, 0};
        if (tid < 128) ((int4*)A8_lds)[tid] = z4;
    }
    __syncthreads();
    if (tid < 16) {
        A8_lds[0][(16 + tid) * 8 + 2] = 0x3F80;  // bias=1.0 at k-local=10
        A8_lds[1][(16 + tid) * 8 + 2] = 0x3F80;
    }
    if (tid < 256 && e_x < EMBD) {
        int tok = xtok[(gb * 16 + m_x) * T_STEPS + 0];
        float v = emb[tok * EMBD + e_x];
        A8_lds[0][(m_x + 16 * (e_x >> 3)) * 8 + (e_x & 7)] = f2bf(v);
    }
    __syncthreads();

    float c0 = 0.0f, c1 = 0.0f;
    int tgt0 = 0, tgt1 = 0;

    for (int t = 0; t < T_STEPS; t++) {
        const int p = t & 1, q = (t + 1) & 1;

        // x(t+1) prefetch (independent)
        float xval = 0.0f;
        const bool do_x = (t < T_STEPS - 1) && (tid < 256) && (e_x < EMBD);
        if ((t < T_STEPS - 1) && (tid < 256)) {
            int tok = xtok[(gb * 16 + m_x) * T_STEPS + (t + 1)];
            if (e_x < EMBD) xval = emb[tok * EMBD + e_x];
        }

        // SYNC-A: wait for all 4 siblings' h(t) -- BOUNDED spin
        if (t > 0) {
            if (tid == 0) {
                const int tg = p ? tgt1 : tgt0;
                int spins = 0;
                while ((int)(__hip_atomic_load(&flags[p * 64 + gb], __ATOMIC_ACQUIRE,
                                               __HIP_MEMORY_SCOPE_AGENT) - (unsigned)tg) < 0) {
                    __builtin_amdgcn_s_sleep(2);
                    if (++spins > 200000) break;  // hang-proof: finish wrong, not dead
                }
            }
            __syncthreads();
        }

        // A-frags for kits 0..7 from exchanged h (t=0: zeros)
        i32x4 af[8];
        if (t > 0) {
            const i32x4* hv = (const i32x4*)(hxc + (size_t)(p * 64 + gb) * 2048);
            const int base = (lane & 15) * 32 + (lane >> 4);   // m*32 + quad
#pragma unroll
            for (int s = 0; s < 8; s++) af[s] = hv[base + s * 4];
        } else {
#pragma unroll
            for (int s = 0; s < 8; s++) af[s] = (i32x4){0, 0, 0, 0};
        }

        f32x4 acc0 = (f32x4){0.f, 0.f, 0.f, 0.f};
        f32x4 acc1 = (f32x4){0.f, 0.f, 0.f, 0.f};
        // kit 8 (x + bias) from A8_lds
        {
            i32x4 a8 = ((const i32x4*)A8_lds[p])[lane];
            acc0 = mfma_v(a8, breg[6][0], acc0);
            acc1 = mfma_v(a8, breg[6][1], acc1);
        }
        // kits 0,1,2,3,4,7 (B in regs)
        {
            const int ks6[6] = {0, 1, 2, 3, 4, 7};
#pragma unroll
            for (int i = 0; i < 6; i++) {
                acc0 = mfma_v(af[ks6[i]], breg[i][0], acc0);
                acc1 = mfma_v(af[ks6[i]], breg[i][1], acc1);
            }
        }
        // kits 5,6 (B in LDS)
#pragma unroll
        for (int k = 0; k < 2; k++) {
            acc0 = mfma_v(af[5 + k], B_lds[(k * 16 + gate * 4 + ntl0 + 0) * 64 + lane], acc0);
            acc1 = mfma_v(af[5 + k], B_lds[(k * 16 + gate * 4 + ntl0 + 1) * 64 + lane], acc1);
        }

        // z -> z_lds (C layout: batch row m = (lane>>4)*4+reg, ncol = lane&15)
        {
            const int col = lane & 15, qd = lane >> 4;
#pragma unroll
            for (int rr = 0; rr < 4; rr++) {
                z_lds[(gate * 16 + qd * 4 + rr) * 66 + (ntl0 + 0) * 16 + col] = acc0[rr];
                z_lds[(gate * 16 + qd * 4 + rr) * 66 + (ntl0 + 1) * 16 + col] = acc1[rr];
            }
        }
        __syncthreads();  // B1: z complete

        // gate math: 2 h-values per thread (row r_gm, hcols hc0/hc0+1)
        float zg[4], zh[4];
#pragma unroll
        for (int g = 0; g < 4; g++) {
            const float2 zz = *(const float2*)&z_lds[(g * 16 + r_gm) * 66 + hc0];
            zg[g] = zz.x; zh[g] = zz.y;
        }
        float hh0, hh1;
        {
            float gg = tanh_fast(zg[0]), ii = sig_fast(zg[1]);
            float ff = sig_fast(zg[2]),  oo = sig_fast(zg[3]);
            float cn = gg * ii + c0 * ff; c0 = cn;
            hh0 = tanh_fast(cn) * oo;
        }
        {
            float gg = tanh_fast(zh[0]), ii = sig_fast(zh[1]);
            float ff = sig_fast(zh[2]),  oo = sig_fast(zh[3]);
            float cn = gg * ii + c1 * ff; c1 = cn;
            hh1 = tanh_fast(cn) * oo;
        }

        if (t < T_STEPS - 1) {
            unsigned int hp;
            asm("v_cvt_pk_bf16_f32 %0, %1, %2" : "=v"(hp) : "v"(hh0), "v"(hh1));
            hxc[(size_t)(q * 64 + gb) * 2048 + r_gm * 128 + ((hg * 64 + hc0) >> 1)] = hp;
            if (do_x)
                A8_lds[q][(m_x + 16 * (e_x >> 3)) * 8 + (e_x & 7)] = f2bf(xval);
            __syncthreads();  // B2: drains vmcnt -> h stores complete
            if (tid == 0)
                __hip_atomic_fetch_add(&flags[q * 64 + gb], 1u,
                                       __ATOMIC_RELEASE, __HIP_MEMORY_SCOPE_AGENT);
            if (q) tgt1 += 4; else tgt0 += 4;
        } else {
            // --- epilogue: project final h (held in hh0/hh1) ---
            if (tid < 160) outacc[tid] = 0.0f;
            __syncthreads();
            const int hcg = hg * 64 + hc0;
            float part[10];
#pragma unroll
            for (int cl = 0; cl < 10; cl++)
                part[cl] = hh0 * Wph[hcg * 10 + cl] + hh1 * Wph[(hcg + 1) * 10 + cl];
#pragma unroll
            for (int cl = 0; cl < 10; cl++)
                atomicAdd(&outacc[r_gm * 10 + cl], part[cl]);
            __syncthreads();
            if (tid < 160) {
                int m = tid / 10, cl = tid - m * 10;
                float v = outacc[tid];
                if (hg == 0) v += bp[cl];     // bias added exactly once per row
                atomicAdd(&out[(gb * 16 + m) * 10 + cl], v);
            }
        }
    }
}

extern "C" void kernel_launch(void* const* d_in, const int* in_sizes, int n_in,
                              void* d_out, int out_size, void* d_ws, size_t ws_size,
                              hipStream_t stream) {
    const int*   x    = (const int*)  d_in[0];
    const float* emb  = (const float*)d_in[1];
    const float* Wgx  = (const float*)d_in[2];
    const float* Wgh  = (const float*)d_in[3];
    const float* bg   = (const float*)d_in[4];
    const float* Wix  = (const float*)d_in[5];
    const float* Wih  = (const float*)d_in[6];
    const float* bi   = (const float*)d_in[7];
    const float* Wfx  = (const float*)d_in[8];
    const float* Wfh  = (const float*)d_in[9];
    const float* bf_  = (const float*)d_in[10];
    const float* Wox  = (const float*)d_in[11];
    const float* Woh  = (const float*)d_in[12];
    const float* bo   = (const float*)d_in[13];
    const float* Wph  = (const float*)d_in[14];
    const float* bp   = (const float*)d_in[15];

    char* ws = (char*)d_ws;
    unsigned short* wswz  = (unsigned short*)ws;                    // 576 KB
    unsigned int*   flags = (unsigned int*)(ws + 589824);           // 1 KB (4K pad)
    unsigned int*   hxc   = (unsigned int*)(ws + 589824 + 4096);    // 1 MB

    build_wswz<<<NBLK_K1, 64, 0, stream>>>(Wgx, Wgh, bg, Wix, Wih, bi,
                                           Wfx, Wfh, bf_, Wox, Woh, bo,
                                           wswz, flags);
    lstm_main<<<NBLK, 512, 0, stream>>>(x, emb, Wph, bp, wswz, flags, hxc,
                                        (float*)d_out);
}

// Round 9
// 1009.390 us; speedup vs baseline: 2.0581x; 2.0581x over previous
//
#include <hip/hip_runtime.h>
#include <stdint.h>

#define T_STEPS 256
#define EMBD 10
#define NKIT 9          // K = 288 = 9*32 (256 h + 10 x + 1 bias + pad)
#define NBLK_K1 (64 * NKIT)
#define NBLK 256        // main grid: 4 hcol-quarters x 64 batch-groups

typedef __attribute__((ext_vector_type(8))) short bf16x8;
typedef __attribute__((ext_vector_type(4))) float f32x4;
typedef __attribute__((ext_vector_type(4))) int   i32x4;

__device__ __forceinline__ unsigned short f2bf(float f) {
    union { float f; unsigned int u; } v; v.f = f;
    unsigned int u = v.u;
    unsigned int r = (u + 0x7FFFu + ((u >> 16) & 1u)) >> 16;  // RNE
    return (unsigned short)r;
}
// R19-proven fast transcendentals (1-ulp): invisible under bf16 h-storage.
__device__ __forceinline__ float sig_fast(float x) {
    return __builtin_amdgcn_rcpf(1.0f + __builtin_amdgcn_exp2f(-1.4426950408889634f * x));
}
__device__ __forceinline__ float tanh_fast(float x) {
    return 1.0f - 2.0f * __builtin_amdgcn_rcpf(__builtin_amdgcn_exp2f(2.8853900817779268f * x) + 1.0f);
}
__device__ __forceinline__ f32x4 mfma_v(i32x4 a, i32x4 b, f32x4 c) {
    return __builtin_amdgcn_mfma_f32_16x16x32_bf16(
        __builtin_bit_cast(bf16x8, a), __builtin_bit_cast(bf16x8, b), c, 0, 0, 0);
}

// R26: per-line coherent comm ops (sc1 = agent scope on gfx940+), replacing
// R25's RELEASE/ACQUIRE whose lowering (buffer_wbl2 / buffer_inv = full-L2
// walks EVERY step by EVERY block) was the 19k-cyc/step cost. Relaxed
// ordering is sufficient: h-stores are sc1 write-through, acked (vmcnt=0,
// drained by the B2 barrier) at the LLC BEFORE the flag fetch_add issues;
// consumer reads bypass the stale-able caches entirely.
__device__ __forceinline__ void load_h8_sc1(const unsigned int* hw, i32x4 af[8]) {
    // 8x dwordx4 sc1 + waitcnt INSIDE one asm block (hazard-safe: outputs
    // not visible to the scheduler until the block ends -- rule #18).
    asm volatile(
        "global_load_dwordx4 %0, %8, off sc1\n\t"
        "global_load_dwordx4 %1, %8, off offset:64 sc1\n\t"
        "global_load_dwordx4 %2, %8, off offset:128 sc1\n\t"
        "global_load_dwordx4 %3, %8, off offset:192 sc1\n\t"
        "global_load_dwordx4 %4, %8, off offset:256 sc1\n\t"
        "global_load_dwordx4 %5, %8, off offset:320 sc1\n\t"
        "global_load_dwordx4 %6, %8, off offset:384 sc1\n\t"
        "global_load_dwordx4 %7, %8, off offset:448 sc1\n\t"
        "s_waitcnt vmcnt(0)"
        : "=&v"(af[0]), "=&v"(af[1]), "=&v"(af[2]), "=&v"(af[3]),
          "=&v"(af[4]), "=&v"(af[5]), "=&v"(af[6]), "=&v"(af[7])
        : "v"(hw)
        : "memory");
}

// ---------------------------------------------------------------------------
// K1: swizzled bf16 weights Wfull[288][1024] in MFMA B-frag order
// [kit 0..8][ntile 0..63][lane] x 16B. Block 0 zeroes ALL flag slots
// (R23 lesson: 64-thread block, guard must loop).
// ---------------------------------------------------------------------------
__global__ __launch_bounds__(64) void build_wswz(
    const float* __restrict__ Wgx, const float* __restrict__ Wgh, const float* __restrict__ bg,
    const float* __restrict__ Wix, const float* __restrict__ Wih, const float* __restrict__ bi,
    const float* __restrict__ Wfx, const float* __restrict__ Wfh, const float* __restrict__ bf_,
    const float* __restrict__ Wox, const float* __restrict__ Woh, const float* __restrict__ bo,
    unsigned short* __restrict__ wswz, unsigned int* __restrict__ flags)
{
    if (blockIdx.x == 0) {
#pragma unroll
        for (int j = 0; j < 4; j++)
            flags[threadIdx.x + 64 * j] = 0u;
    }

    int g   = blockIdx.x / NKIT;   // ntile
    int kit = blockIdx.x % NKIT;
    int lane = threadIdx.x;
    int n = g * 16 + (lane & 15);
    int q = n >> 8;
    int col = n & 255;
    const float* Wh = (q == 0) ? Wgh : (q == 1) ? Wih : (q == 2) ? Wfh : Woh;
    const float* Wx = (q == 0) ? Wgx : (q == 1) ? Wix : (q == 2) ? Wfx : Wox;
    const float* bb = (q == 0) ? bg  : (q == 1) ? bi  : (q == 2) ? bf_ : bo;
    int k0 = kit * 32 + (lane >> 4) * 8;

    int4 out;
    unsigned short* p = (unsigned short*)&out;
#pragma unroll
    for (int jx = 0; jx < 8; jx++) {
        int k = k0 + jx;
        float v = 0.0f;
        if (k < 256)             v = Wh[k * 256 + col];
        else if (k < 256 + EMBD) v = Wx[(k - 256) * 256 + col];
        else if (k == 266)       v = bb[col];
        p[jx] = f2bf(v);
    }
    ((int4*)wswz)[(kit * 64 + g) * 64 + lane] = out;
}

// ---------------------------------------------------------------------------
// K2: N-SPLIT persistent LSTM (R25 structure, verified correct; comm ops
// swapped to relaxed+sc1). 256 blocks x 512 threads, 1/CU.
// blk = hg*64 + gb. Per wave: gate = w&3, 2 local ntiles -> 18 MFMAs/step.
// B: 7 kits in 56 regs, kits {5,6} in 32 KB LDS.
// h-exchange protocol per step among 4 siblings:
//   producer: sc1 h store (write-through to LLC) -> B2 __syncthreads
//             (vmcnt drain = stores acked at LLC) -> flag fetch_add RELAXED
//   consumer: tid0 BOUNDED spin, RELAXED sc1 flag load -> __syncthreads ->
//             8x dwordx4 sc1 h loads (always-fresh; no cached path)
// NO wbl2 / NO inv anywhere (R25's 19k-cyc/step killer).
// Deadlock-free capacity: launch_bounds(512,4) + ~52 KB LDS => 2 blocks/CU,
// grid = 1/CU. Spin stays bounded (hang-proof; never fires when correct).
// ---------------------------------------------------------------------------
__global__ __launch_bounds__(512, 4)
void lstm_main(
    const int*   __restrict__ xtok,   // [1024][1][256]
    const float* __restrict__ emb,    // [32000][10]
    const float* __restrict__ Wph,    // [256][10]
    const float* __restrict__ bp,     // [10]
    const unsigned short* __restrict__ wswz,
    unsigned int* __restrict__ flags, // [2][64]
    unsigned int* __restrict__ hxc,   // [2][64][16][128] u32 (2 bf16 each)
    float* __restrict__ out)          // [1024][10]
{
    __shared__ __align__(16) unsigned short A8_lds[2][64 * 8];  // 2 KB (kit 8: x+bias)
    __shared__ __align__(16) i32x4 B_lds[2 * 16 * 64];          // 32 KB (kits 5,6)
    __shared__ float z_lds[4 * 16 * 66];                        // 16.5 KB (padded 66)
    __shared__ float outacc[160];

    const int tid  = threadIdx.x;
    const int w    = tid >> 6;        // wave 0..7
    const int lane = tid & 63;
    const int blk  = blockIdx.x;
    const int gb   = blk & 63;        // batch group
    const int hg   = blk >> 6;        // hcol quarter 0..3

    const int gate = w & 3;
    const int ntl0 = (w >> 2) * 2;    // local h-ntile pair base (0 or 2)

    const int m_x = tid >> 4;         // x-gather row (tid<256)
    const int e_x = tid & 15;

    const int r_gm = tid >> 5;        // gate-math row 0..15
    const int hc0  = (tid * 2) & 63;  // gate-math col pair base (even)

    const i32x4* Bg = (const i32x4*)wswz;

    // --- B prologue: regs for kits {0,1,2,3,4,7,8} (56 VGPRs) ---
    i32x4 breg[7][2];
    {
        const int ks[7] = {0, 1, 2, 3, 4, 7, 8};
#pragma unroll
        for (int i = 0; i < 7; i++)
#pragma unroll
            for (int jj = 0; jj < 2; jj++) {
                int ntile = gate * 16 + hg * 4 + ntl0 + jj;
                breg[i][jj] = Bg[(ks[i] * 64 + ntile) * 64 + lane];
            }
    }
    // --- B LDS: kits 5,6 for this block's 16 ntiles ---
    for (int i = tid; i < 2 * 16 * 64; i += 512) {
        int k   = i >> 10;          // 0->kit5, 1->kit6
        int ntl = (i >> 6) & 15;    // local ntile = gt*4 + j
        int ln  = i & 63;
        int gt = ntl >> 2, j = ntl & 3;
        B_lds[i] = Bg[((5 + k) * 64 + gt * 16 + hg * 4 + j) * 64 + ln];
    }

    // --- A8 init: zeros, bias (both parities), x_0 (parity 0) ---
    {
        int4 z4 = {0, 0, 0, 0};
        if (tid < 128) ((int4*)A8_lds)[tid] = z4;
    }
    __syncthreads();
    if (tid < 16) {
        A8_lds[0][(16 + tid) * 8 + 2] = 0x3F80;  // bias=1.0 at k-local=10
        A8_lds[1][(16 + tid) * 8 + 2] = 0x3F80;
    }
    if (tid < 256 && e_x < EMBD) {
        int tok = xtok[(gb * 16 + m_x) * T_STEPS + 0];
        float v = emb[tok * EMBD + e_x];
        A8_lds[0][(m_x + 16 * (e_x >> 3)) * 8 + (e_x & 7)] = f2bf(v);
    }
    __syncthreads();

    float c0 = 0.0f, c1 = 0.0f;
    int tgt0 = 0, tgt1 = 0;

    // per-lane h-read base (u32 units): row (lane&15), kit-quad (lane>>4)
    const unsigned int* hwbase = hxc + ((lane & 15) * 128 + (lane >> 4) * 4);

    for (int t = 0; t < T_STEPS; t++) {
        const int p = t & 1, q = (t + 1) & 1;

        // x(t+1) prefetch (independent)
        float xval = 0.0f;
        const bool do_x = (t < T_STEPS - 1) && (tid < 256) && (e_x < EMBD);
        if ((t < T_STEPS - 1) && (tid < 256)) {
            int tok = xtok[(gb * 16 + m_x) * T_STEPS + (t + 1)];
            if (e_x < EMBD) xval = emb[tok * EMBD + e_x];
        }

        // SYNC-A: wait for all 4 siblings' h(t) -- BOUNDED spin, RELAXED sc1
        if (t > 0) {
            if (tid == 0) {
                const int tg = p ? tgt1 : tgt0;
                int spins = 0;
                while ((int)(__hip_atomic_load(&flags[p * 64 + gb], __ATOMIC_RELAXED,
                                               __HIP_MEMORY_SCOPE_AGENT) - (unsigned)tg) < 0) {
                    __builtin_amdgcn_s_sleep(2);
                    if (++spins > 200000) break;  // hang-proof: finish wrong, not dead
                }
            }
            __syncthreads();
        }

        // A-frags for kits 0..7 from exchanged h (t=0: zeros)
        i32x4 af[8];
        if (t > 0) {
            load_h8_sc1(hwbase + (size_t)(p * 64 + gb) * 2048, af);
        } else {
#pragma unroll
            for (int s = 0; s < 8; s++) af[s] = (i32x4){0, 0, 0, 0};
        }

        f32x4 acc0 = (f32x4){0.f, 0.f, 0.f, 0.f};
        f32x4 acc1 = (f32x4){0.f, 0.f, 0.f, 0.f};
        // kit 8 (x + bias) from A8_lds
        {
            i32x4 a8 = ((const i32x4*)A8_lds[p])[lane];
            acc0 = mfma_v(a8, breg[6][0], acc0);
            acc1 = mfma_v(a8, breg[6][1], acc1);
        }
        // kits 0,1,2,3,4,7 (B in regs)
        {
            const int ks6[6] = {0, 1, 2, 3, 4, 7};
#pragma unroll
            for (int i = 0; i < 6; i++) {
                acc0 = mfma_v(af[ks6[i]], breg[i][0], acc0);
                acc1 = mfma_v(af[ks6[i]], breg[i][1], acc1);
            }
        }
        // kits 5,6 (B in LDS)
#pragma unroll
        for (int k = 0; k < 2; k++) {
            acc0 = mfma_v(af[5 + k], B_lds[(k * 16 + gate * 4 + ntl0 + 0) * 64 + lane], acc0);
            acc1 = mfma_v(af[5 + k], B_lds[(k * 16 + gate * 4 + ntl0 + 1) * 64 + lane], acc1);
        }

        // z -> z_lds (C layout: batch row m = (lane>>4)*4+reg, ncol = lane&15)
        {
            const int col = lane & 15, qd = lane >> 4;
#pragma unroll
            for (int rr = 0; rr < 4; rr++) {
                z_lds[(gate * 16 + qd * 4 + rr) * 66 + (ntl0 + 0) * 16 + col] = acc0[rr];
                z_lds[(gate * 16 + qd * 4 + rr) * 66 + (ntl0 + 1) * 16 + col] = acc1[rr];
            }
        }
        __syncthreads();  // B1: z complete

        // gate math: 2 h-values per thread (row r_gm, hcols hc0/hc0+1)
        float zg[4], zh[4];
#pragma unroll
        for (int g = 0; g < 4; g++) {
            const float2 zz = *(const float2*)&z_lds[(g * 16 + r_gm) * 66 + hc0];
            zg[g] = zz.x; zh[g] = zz.y;
        }
        float hh0, hh1;
        {
            float gg = tanh_fast(zg[0]), ii = sig_fast(zg[1]);
            float ff = sig_fast(zg[2]),  oo = sig_fast(zg[3]);
            float cn = gg * ii + c0 * ff; c0 = cn;
            hh0 = tanh_fast(cn) * oo;
        }
        {
            float gg = tanh_fast(zh[0]), ii = sig_fast(zh[1]);
            float ff = sig_fast(zh[2]),  oo = sig_fast(zh[3]);
            float cn = gg * ii + c1 * ff; c1 = cn;
            hh1 = tanh_fast(cn) * oo;
        }

        if (t < T_STEPS - 1) {
            unsigned int hp;
            asm("v_cvt_pk_bf16_f32 %0, %1, %2" : "=v"(hp) : "v"(hh0), "v"(hh1));
            // sc1 write-through: visible at LLC once vmcnt retires (B2 drain)
            __hip_atomic_store(
                &hxc[(size_t)(q * 64 + gb) * 2048 + r_gm * 128 + ((hg * 64 + hc0) >> 1)],
                hp, __ATOMIC_RELAXED, __HIP_MEMORY_SCOPE_AGENT);
            if (do_x)
                A8_lds[q][(m_x + 16 * (e_x >> 3)) * 8 + (e_x & 7)] = f2bf(xval);
            __syncthreads();  // B2: drains vmcnt -> h stores acked at LLC
            if (tid == 0)
                __hip_atomic_fetch_add(&flags[q * 64 + gb], 1u,
                                       __ATOMIC_RELAXED, __HIP_MEMORY_SCOPE_AGENT);
            if (q) tgt1 += 4; else tgt0 += 4;
        } else {
            // --- epilogue: project final h (held in hh0/hh1) ---
            if (tid < 160) outacc[tid] = 0.0f;
            __syncthreads();
            const int hcg = hg * 64 + hc0;
            float part[10];
#pragma unroll
            for (int cl = 0; cl < 10; cl++)
                part[cl] = hh0 * Wph[hcg * 10 + cl] + hh1 * Wph[(hcg + 1) * 10 + cl];
#pragma unroll
            for (int cl = 0; cl < 10; cl++)
                atomicAdd(&outacc[r_gm * 10 + cl], part[cl]);
            __syncthreads();
            if (tid < 160) {
                int m = tid / 10, cl = tid - m * 10;
                float v = outacc[tid];
                if (hg == 0) v += bp[cl];     // bias added exactly once per row
                atomicAdd(&out[(gb * 16 + m) * 10 + cl], v);
            }
        }
    }
}

extern "C" void kernel_launch(void* const* d_in, const int* in_sizes, int n_in,
                              void* d_out, int out_size, void* d_ws, size_t ws_size,
                              hipStream_t stream) {
    const int*   x    = (const int*)  d_in[0];
    const float* emb  = (const float*)d_in[1];
    const float* Wgx  = (const float*)d_in[2];
    const float* Wgh  = (const float*)d_in[3];
    const float* bg   = (const float*)d_in[4];
    const float* Wix  = (const float*)d_in[5];
    const float* Wih  = (const float*)d_in[6];
    const float* bi   = (const float*)d_in[7];
    const float* Wfx  = (const float*)d_in[8];
    const float* Wfh  = (const float*)d_in[9];
    const float* bf_  = (const float*)d_in[10];
    const float* Wox  = (const float*)d_in[11];
    const float* Woh  = (const float*)d_in[12];
    const float* bo   = (const float*)d_in[13];
    const float* Wph  = (const float*)d_in[14];
    const float* bp   = (const float*)d_in[15];

    char* ws = (char*)d_ws;
    unsigned short* wswz  = (unsigned short*)ws;                    // 576 KB
    unsigned int*   flags = (unsigned int*)(ws + 589824);           // 1 KB (4K pad)
    unsigned int*   hxc   = (unsigned int*)(ws + 589824 + 4096);    // 1 MB

    build_wswz<<<NBLK_K1, 64, 0, stream>>>(Wgx, Wgh, bg, Wix, Wih, bi,
                                           Wfx, Wfh, bf_, Wox, Woh, bo,
                                           wswz, flags);
    lstm_main<<<NBLK, 512, 0, stream>>>(x, emb, Wph, bp, wswz, flags, hxc,
                                        (float*)d_out);
}

// Round 11
// 706.931 us; speedup vs baseline: 2.9387x; 1.4278x over previous
//
#include <hip/hip_runtime.h>
#include <stdint.h>

#define T_STEPS 256
#define EMBD 10
#define NKIT 9          // K = 288 = 9*32 (256 h + 10 x + 1 bias + pad)
#define NBLK_K1 (64 * NKIT)
#define NBLK 256        // main grid: 4 hcol-quarters x 64 batch-groups

typedef __attribute__((ext_vector_type(8))) short bf16x8;
typedef __attribute__((ext_vector_type(4))) float f32x4;
typedef __attribute__((ext_vector_type(4))) int   i32x4;

__device__ __forceinline__ unsigned short f2bf(float f) {
    union { float f; unsigned int u; } v; v.f = f;
    unsigned int u = v.u;
    unsigned int r = (u + 0x7FFFu + ((u >> 16) & 1u)) >> 16;  // RNE
    return (unsigned short)r;
}
__device__ __forceinline__ float sig_fast(float x) {
    return __builtin_amdgcn_rcpf(1.0f + __builtin_amdgcn_exp2f(-1.4426950408889634f * x));
}
__device__ __forceinline__ float tanh_fast(float x) {
    return 1.0f - 2.0f * __builtin_amdgcn_rcpf(__builtin_amdgcn_exp2f(2.8853900817779268f * x) + 1.0f);
}
__device__ __forceinline__ f32x4 mfma_v(i32x4 a, i32x4 b, f32x4 c) {
    return __builtin_amdgcn_mfma_f32_16x16x32_bf16(
        __builtin_bit_cast(bf16x8, a), __builtin_bit_cast(bf16x8, b), c, 0, 0, 0);
}

// ---------------------------------------------------------------------------
// K1: swizzled bf16 weights [kit][ntile][lane] x 16B. Block 0 zeroes all
// 256 flag slots (R23 lesson: 64-thread block, loop the guard).
// ---------------------------------------------------------------------------
__global__ __launch_bounds__(64) void build_wswz(
    const float* __restrict__ Wgx, const float* __restrict__ Wgh, const float* __restrict__ bg,
    const float* __restrict__ Wix, const float* __restrict__ Wih, const float* __restrict__ bi,
    const float* __restrict__ Wfx, const float* __restrict__ Wfh, const float* __restrict__ bf_,
    const float* __restrict__ Wox, const float* __restrict__ Woh, const float* __restrict__ bo,
    unsigned short* __restrict__ wswz, unsigned int* __restrict__ flags)
{
    if (blockIdx.x == 0) {
#pragma unroll
        for (int j = 0; j < 4; j++)
            flags[threadIdx.x + 64 * j] = 0u;
    }

    int g   = blockIdx.x / NKIT;   // ntile
    int kit = blockIdx.x % NKIT;
    int lane = threadIdx.x;
    int n = g * 16 + (lane & 15);
    int q = n >> 8;
    int col = n & 255;
    const float* Wh = (q == 0) ? Wgh : (q == 1) ? Wih : (q == 2) ? Wfh : Woh;
    const float* Wx = (q == 0) ? Wgx : (q == 1) ? Wix : (q == 2) ? Wfx : Wox;
    const float* bb = (q == 0) ? bg  : (q == 1) ? bi  : (q == 2) ? bf_ : bo;
    int k0 = kit * 32 + (lane >> 4) * 8;

    int4 out;
    unsigned short* p = (unsigned short*)&out;
#pragma unroll
    for (int jx = 0; jx < 8; jx++) {
        int k = k0 + jx;
        float v = 0.0f;
        if (k < 256)             v = Wh[k * 256 + col];
        else if (k < 256 + EMBD) v = Wx[(k - 256) * 256 + col];
        else if (k == 266)       v = bb[col];
        p[jx] = f2bf(v);
    }
    ((int4*)wswz)[(kit * 64 + g) * 64 + lane] = out;
}

// ---------------------------------------------------------------------------
// K2: N-SPLIT persistent LSTM, R26's VERIFIED protocol (sc1/LLC everywhere,
// RMW posts, bounded spin) + R28's fix of R26's real bottleneck:
// R26 had every one of the 8 waves load the SAME 8 KB h-block from the LLC
// (hwbase was lane-only) -> 64 KB/block-step -> ~4.3 TB/s sustained uncached
// LLC reads = the ~9k-cyc step. R28 stages h ONCE per block into LDS
// (512 threads x one 16B sc1 load = 8 KB), then af comes from LDS.
//   stage:  asm sc1 dwordx4 (issue) -> kit8 MFMAs overlap ->
//           s_waitcnt vmcnt(0) + sched_barrier(0)  [rule 18] ->
//           ds_write_b128 -> __syncthreads -> af = LDS reads
// LDS h-buffer padded to 132 u32/row: af ds_read_b128 lands on the
// inherent 64-lane x 16B floor (no super-conflicts).
// R27's same-XCD plain-L2 path is ABANDONED (engaged via matching XCC_IDs
// yet produced stale h + invisible flags; mechanism unresolvable without
// ISA probes).
// ---------------------------------------------------------------------------
__global__ __launch_bounds__(512, 4)
void lstm_main(
    const int*   __restrict__ xtok,   // [1024][1][256]
    const float* __restrict__ emb,    // [32000][10]
    const float* __restrict__ Wph,    // [256][10]
    const float* __restrict__ bp,     // [10]
    const unsigned short* __restrict__ wswz,
    unsigned int* __restrict__ flags, // [2][64]
    unsigned int* __restrict__ hxc,   // [2][64][16][128] u32 (2 bf16 each)
    float* __restrict__ out)          // [1024][10]
{
    __shared__ __align__(16) unsigned short A8_lds[2][64 * 8];  // 2 KB (kit 8: x+bias)
    __shared__ __align__(16) i32x4 B_lds[2 * 16 * 64];          // 32 KB (kits 5,6)
    __shared__ __align__(16) unsigned int Ah_lds[16 * 132];     // 8.25 KB (staged h, padded)
    __shared__ float z_lds[4 * 16 * 66];                        // 16.5 KB (padded 66)
    __shared__ float outacc[160];

    const int tid  = threadIdx.x;
    const int w    = tid >> 6;        // wave 0..7
    const int lane = tid & 63;
    const int blk  = blockIdx.x;
    const int gb   = blk & 63;        // batch group
    const int hg   = blk >> 6;        // hcol quarter 0..3

    const int gate = w & 3;
    const int ntl0 = (w >> 2) * 2;    // local h-ntile pair base (0 or 2)

    const int m_x = tid >> 4;         // x-gather row (tid<256)
    const int e_x = tid & 15;

    const int r_gm = tid >> 5;        // gate-math row 0..15
    const int hc0  = (tid * 2) & 63;  // gate-math col pair base (even)

    const i32x4* Bg = (const i32x4*)wswz;

    // --- B prologue: regs for kits {0,1,2,3,4,7,8} (56 VGPRs) ---
    i32x4 breg[7][2];
    {
        const int ks[7] = {0, 1, 2, 3, 4, 7, 8};
#pragma unroll
        for (int i = 0; i < 7; i++)
#pragma unroll
            for (int jj = 0; jj < 2; jj++) {
                int ntile = gate * 16 + hg * 4 + ntl0 + jj;
                breg[i][jj] = Bg[(ks[i] * 64 + ntile) * 64 + lane];
            }
    }
    // --- B LDS: kits 5,6 for this block's 16 ntiles ---
    for (int i = tid; i < 2 * 16 * 64; i += 512) {
        int k   = i >> 10;          // 0->kit5, 1->kit6
        int ntl = (i >> 6) & 15;    // local ntile = gt*4 + j
        int ln  = i & 63;
        int gt = ntl >> 2, j = ntl & 3;
        B_lds[i] = Bg[((5 + k) * 64 + gt * 16 + hg * 4 + j) * 64 + ln];
    }

    // --- A8 init: zeros, bias (both parities), x_0 (parity 0) ---
    {
        int4 z4 = {0, 0, 0, 0};
        if (tid < 128) ((int4*)A8_lds)[tid] = z4;
    }
    __syncthreads();
    if (tid < 16) {
        A8_lds[0][(16 + tid) * 8 + 2] = 0x3F80;  // bias=1.0 at k-local=10
        A8_lds[1][(16 + tid) * 8 + 2] = 0x3F80;
    }
    if (tid < 256 && e_x < EMBD) {
        int tok = xtok[(gb * 16 + m_x) * T_STEPS + 0];
        float v = emb[tok * EMBD + e_x];
        A8_lds[0][(m_x + 16 * (e_x >> 3)) * 8 + (e_x & 7)] = f2bf(v);
    }
    __syncthreads();

    float c0 = 0.0f, c1 = 0.0f;
    int tgt0 = 0, tgt1 = 0;

    // af LDS read base (i32x4 units): row (lane&15) * 33 + quad; af[s] at +4s
    const int ah_rd = (lane & 15) * 33 + (lane >> 4);
    // staging write slot (i32x4 units): logical row (tid>>5), col (tid&31)
    const int ah_wr = (tid >> 5) * 33 + (tid & 31);

    for (int t = 0; t < T_STEPS; t++) {
        const int p = t & 1, q = (t + 1) & 1;

        // x(t+1) prefetch (independent)
        float xval = 0.0f;
        const bool do_x = (t < T_STEPS - 1) && (tid < 256) && (e_x < EMBD);
        if ((t < T_STEPS - 1) && (tid < 256)) {
            int tok = xtok[(gb * 16 + m_x) * T_STEPS + (t + 1)];
            if (e_x < EMBD) xval = emb[tok * EMBD + e_x];
        }

        // SYNC-A: wait for all 4 siblings' h(t) -- BOUNDED spin (R26-proven)
        if (t > 0) {
            if (tid == 0) {
                const int tg = p ? tgt1 : tgt0;
                int spins = 0;
                while ((int)(__hip_atomic_load(&flags[p * 64 + gb], __ATOMIC_RELAXED,
                                               __HIP_MEMORY_SCOPE_AGENT) - (unsigned)tg) < 0) {
                    __builtin_amdgcn_s_sleep(2);
                    if (++spins > 200000) break;  // hang-proof: finish wrong, not dead
                }
            }
            __syncthreads();
        }

        // stage h(t) ISSUE: one coalesced 16B sc1 load per thread (8 KB/block)
        i32x4 hstage;
        if (t > 0) {
            const unsigned int* sp = hxc + (size_t)(p * 64 + gb) * 2048 + tid * 4;
            asm volatile("global_load_dwordx4 %0, %1, off sc1"
                         : "=&v"(hstage) : "v"(sp) : "memory");
        }

        f32x4 acc0 = (f32x4){0.f, 0.f, 0.f, 0.f};
        f32x4 acc1 = (f32x4){0.f, 0.f, 0.f, 0.f};
        // kit 8 (x + bias; h-independent) overlaps the in-flight stage load
        {
            i32x4 a8 = ((const i32x4*)A8_lds[p])[lane];
            acc0 = mfma_v(a8, breg[6][0], acc0);
            acc1 = mfma_v(a8, breg[6][1], acc1);
        }

        // land staged h into LDS (rule-18 fence), then read af fragments
        i32x4 af[8];
        if (t > 0) {
            asm volatile("s_waitcnt vmcnt(0)" ::: "memory");
            __builtin_amdgcn_sched_barrier(0);
            ((i32x4*)Ah_lds)[ah_wr] = hstage;
            __syncthreads();
#pragma unroll
            for (int s = 0; s < 8; s++)
                af[s] = ((const i32x4*)Ah_lds)[ah_rd + s * 4];
        } else {
#pragma unroll
            for (int s = 0; s < 8; s++) af[s] = (i32x4){0, 0, 0, 0};
        }

        // kits 0,1,2,3,4,7 (B in regs)
        {
            const int ks6[6] = {0, 1, 2, 3, 4, 7};
#pragma unroll
            for (int i = 0; i < 6; i++) {
                acc0 = mfma_v(af[ks6[i]], breg[i][0], acc0);
                acc1 = mfma_v(af[ks6[i]], breg[i][1], acc1);
            }
        }
        // kits 5,6 (B in LDS)
#pragma unroll
        for (int k = 0; k < 2; k++) {
            acc0 = mfma_v(af[5 + k], B_lds[(k * 16 + gate * 4 + ntl0 + 0) * 64 + lane], acc0);
            acc1 = mfma_v(af[5 + k], B_lds[(k * 16 + gate * 4 + ntl0 + 1) * 64 + lane], acc1);
        }

        // z -> z_lds (C layout: batch row m = (lane>>4)*4+reg, ncol = lane&15)
        {
            const int col = lane & 15, qd = lane >> 4;
#pragma unroll
            for (int rr = 0; rr < 4; rr++) {
                z_lds[(gate * 16 + qd * 4 + rr) * 66 + (ntl0 + 0) * 16 + col] = acc0[rr];
                z_lds[(gate * 16 + qd * 4 + rr) * 66 + (ntl0 + 1) * 16 + col] = acc1[rr];
            }
        }
        __syncthreads();  // B1: z complete (also retires af reads before next stage)

        // gate math: 2 h-values per thread (row r_gm, hcols hc0/hc0+1)
        float zg[4], zh[4];
#pragma unroll
        for (int g = 0; g < 4; g++) {
            const float2 zz = *(const float2*)&z_lds[(g * 16 + r_gm) * 66 + hc0];
            zg[g] = zz.x; zh[g] = zz.y;
        }
        float hh0, hh1;
        {
            float gg = tanh_fast(zg[0]), ii = sig_fast(zg[1]);
            float ff = sig_fast(zg[2]),  oo = sig_fast(zg[3]);
            float cn = gg * ii + c0 * ff; c0 = cn;
            hh0 = tanh_fast(cn) * oo;
        }
        {
            float gg = tanh_fast(zh[0]), ii = sig_fast(zh[1]);
            float ff = sig_fast(zh[2]),  oo = sig_fast(zh[3]);
            float cn = gg * ii + c1 * ff; c1 = cn;
            hh1 = tanh_fast(cn) * oo;
        }

        if (t < T_STEPS - 1) {
            unsigned int hp;
            asm("v_cvt_pk_bf16_f32 %0, %1, %2" : "=v"(hp) : "v"(hh0), "v"(hh1));
            // sc1 write-through: visible at LLC once vmcnt retires (B2 drain)
            __hip_atomic_store(
                &hxc[(size_t)(q * 64 + gb) * 2048 + r_gm * 128 + ((hg * 64 + hc0) >> 1)],
                hp, __ATOMIC_RELAXED, __HIP_MEMORY_SCOPE_AGENT);
            if (do_x)
                A8_lds[q][(m_x + 16 * (e_x >> 3)) * 8 + (e_x & 7)] = f2bf(xval);
            __syncthreads();  // B2: drains vmcnt -> h stores acked at LLC
            if (tid == 0)
                __hip_atomic_fetch_add(&flags[q * 64 + gb], 1u,
                                       __ATOMIC_RELAXED, __HIP_MEMORY_SCOPE_AGENT);
            if (q) tgt1 += 4; else tgt0 += 4;
        } else {
            // --- epilogue: project final h (held in hh0/hh1) ---
            if (tid < 160) outacc[tid] = 0.0f;
            __syncthreads();
            const int hcg = hg * 64 + hc0;
            float part[10];
#pragma unroll
            for (int cl = 0; cl < 10; cl++)
                part[cl] = hh0 * Wph[hcg * 10 + cl] + hh1 * Wph[(hcg + 1) * 10 + cl];
#pragma unroll
            for (int cl = 0; cl < 10; cl++)
                atomicAdd(&outacc[r_gm * 10 + cl], part[cl]);
            __syncthreads();
            if (tid < 160) {
                int m = tid / 10, cl = tid - m * 10;
                float v = outacc[tid];
                if (hg == 0) v += bp[cl];     // bias added exactly once per row
                atomicAdd(&out[(gb * 16 + m) * 10 + cl], v);
            }
        }
    }
}

extern "C" void kernel_launch(void* const* d_in, const int* in_sizes, int n_in,
                              void* d_out, int out_size, void* d_ws, size_t ws_size,
                              hipStream_t stream) {
    const int*   x    = (const int*)  d_in[0];
    const float* emb  = (const float*)d_in[1];
    const float* Wgx  = (const float*)d_in[2];
    const float* Wgh  = (const float*)d_in[3];
    const float* bg   = (const float*)d_in[4];
    const float* Wix  = (const float*)d_in[5];
    const float* Wih  = (const float*)d_in[6];
    const float* bi   = (const float*)d_in[7];
    const float* Wfx  = (const float*)d_in[8];
    const float* Wfh  = (const float*)d_in[9];
    const float* bf_  = (const float*)d_in[10];
    const float* Wox  = (const float*)d_in[11];
    const float* Woh  = (const float*)d_in[12];
    const float* bo   = (const float*)d_in[13];
    const float* Wph  = (const float*)d_in[14];
    const float* bp   = (const float*)d_in[15];

    char* ws = (char*)d_ws;
    unsigned short* wswz  = (unsigned short*)ws;                    // 576 KB
    unsigned int*   flags = (unsigned int*)(ws + 589824);           // 1 KB (4K pad)
    unsigned int*   hxc   = (unsigned int*)(ws + 589824 + 4096);    // 1 MB

    build_wswz<<<NBLK_K1, 64, 0, stream>>>(Wgx, Wgh, bg, Wix, Wih, bi,
                                           Wfx, Wfh, bf_, Wox, Woh, bo,
                                           wswz, flags);
    lstm_main<<<NBLK, 512, 0, stream>>>(x, emb, Wph, bp, wswz, flags, hxc,
                                        (float*)d_out);
}

// Round 12
// 676.830 us; speedup vs baseline: 3.0693x; 1.0445x over previous
//
#include <hip/hip_runtime.h>
#include <stdint.h>

#define T_STEPS 256
#define EMBD 10
#define NKIT 9          // K = 288 = 9*32 (256 h + 10 x + 1 bias + pad)
#define NBLK_K1 (64 * NKIT)
#define NBLK 256        // main grid: 4 hcol-quarters x 64 batch-groups

typedef __attribute__((ext_vector_type(8))) short bf16x8;
typedef __attribute__((ext_vector_type(4))) float f32x4;
typedef __attribute__((ext_vector_type(4))) int   i32x4;

__device__ __forceinline__ unsigned short f2bf(float f) {
    union { float f; unsigned int u; } v; v.f = f;
    unsigned int u = v.u;
    unsigned int r = (u + 0x7FFFu + ((u >> 16) & 1u)) >> 16;  // RNE
    return (unsigned short)r;
}
__device__ __forceinline__ float sig_fast(float x) {
    return __builtin_amdgcn_rcpf(1.0f + __builtin_amdgcn_exp2f(-1.4426950408889634f * x));
}
__device__ __forceinline__ float tanh_fast(float x) {
    return 1.0f - 2.0f * __builtin_amdgcn_rcpf(__builtin_amdgcn_exp2f(2.8853900817779268f * x) + 1.0f);
}
__device__ __forceinline__ f32x4 mfma_v(i32x4 a, i32x4 b, f32x4 c) {
    return __builtin_amdgcn_mfma_f32_16x16x32_bf16(
        __builtin_bit_cast(bf16x8, a), __builtin_bit_cast(bf16x8, b), c, 0, 0, 0);
}

// ---------------------------------------------------------------------------
// K1: swizzled bf16 weights [kit][ntile][lane] x 16B. Block 0 zeroes ALL
// 512 flag dwords ([2 parity][64 group][4 producer]) -- R23 lesson: loop.
// ---------------------------------------------------------------------------
__global__ __launch_bounds__(64) void build_wswz(
    const float* __restrict__ Wgx, const float* __restrict__ Wgh, const float* __restrict__ bg,
    const float* __restrict__ Wix, const float* __restrict__ Wih, const float* __restrict__ bi,
    const float* __restrict__ Wfx, const float* __restrict__ Wfh, const float* __restrict__ bf_,
    const float* __restrict__ Wox, const float* __restrict__ Woh, const float* __restrict__ bo,
    unsigned short* __restrict__ wswz, unsigned int* __restrict__ flags)
{
    if (blockIdx.x == 0) {
#pragma unroll
        for (int j = 0; j < 8; j++)
            flags[threadIdx.x + 64 * j] = 0u;
    }

    int g   = blockIdx.x / NKIT;   // ntile
    int kit = blockIdx.x % NKIT;
    int lane = threadIdx.x;
    int n = g * 16 + (lane & 15);
    int q = n >> 8;
    int col = n & 255;
    const float* Wh = (q == 0) ? Wgh : (q == 1) ? Wih : (q == 2) ? Wfh : Woh;
    const float* Wx = (q == 0) ? Wgx : (q == 1) ? Wix : (q == 2) ? Wfx : Wox;
    const float* bb = (q == 0) ? bg  : (q == 1) ? bi  : (q == 2) ? bf_ : bo;
    int k0 = kit * 32 + (lane >> 4) * 8;

    int4 out;
    unsigned short* p = (unsigned short*)&out;
#pragma unroll
    for (int jx = 0; jx < 8; jx++) {
        int k = k0 + jx;
        float v = 0.0f;
        if (k < 256)             v = Wh[k * 256 + col];
        else if (k < 256 + EMBD) v = Wx[(k - 256) * 256 + col];
        else if (k == 266)       v = bb[col];
        p[jx] = f2bf(v);
    }
    ((int4*)wswz)[(kit * 64 + g) * 64 + lane] = out;
}

// ---------------------------------------------------------------------------
// K2: N-SPLIT persistent LSTM (R28 verified base: sc1/LLC comm + per-block
// LDS h-staging). R29 protocol tuning, mechanics unchanged:
//  (1) DISTRIBUTED poll: each staging thread's 16B comes from exactly one
//      producer quarter myq=(tid&31)>>3 -> thread polls ONLY flags[p][gb][myq]
//      (plain dword, value = step#) and issues its stage load immediately.
//      Removes tid0 poll bottleneck + the post-poll broadcast barrier;
//      absorbs producer skew per-thread.
//  (2) Per-producer flag slots, posted with plain value STORES (t+1), not
//      fetch_add: no 4-way RMW serialization on one line. Monotonic + init-0
//      + wrap-safe compare => same safety as R26/R28 counters.
//  (3) Own-quarter h never round-trips the LLC: written straight into
//      Ah_lds at the step tail (af-reads of the current step completed
//      before B1, so no WAR); own-quarter threads skip poll+stage.
// Ordering audit unchanged: posts happen after B2 vmcnt-drain (h acked at
// LLC before flag store issues); parity ping-pong still orders slot reuse
// behind sibling reads. Spin stays bounded (hang-proof).
// ---------------------------------------------------------------------------
__global__ __launch_bounds__(512, 4)
void lstm_main(
    const int*   __restrict__ xtok,   // [1024][1][256]
    const float* __restrict__ emb,    // [32000][10]
    const float* __restrict__ Wph,    // [256][10]
    const float* __restrict__ bp,     // [10]
    const unsigned short* __restrict__ wswz,
    unsigned int* __restrict__ flags, // [2][64][4] value-flags
    unsigned int* __restrict__ hxc,   // [2][64][16][128] u32 (2 bf16 each)
    float* __restrict__ out)          // [1024][10]
{
    __shared__ __align__(16) unsigned short A8_lds[2][64 * 8];  // 2 KB (kit 8: x+bias)
    __shared__ __align__(16) i32x4 B_lds[2 * 16 * 64];          // 32 KB (kits 5,6)
    __shared__ __align__(16) unsigned int Ah_lds[16 * 132];     // 8.25 KB (staged h, padded)
    __shared__ float z_lds[4 * 16 * 66];                        // 16.5 KB (padded 66)
    __shared__ float outacc[160];

    const int tid  = threadIdx.x;
    const int w    = tid >> 6;        // wave 0..7
    const int lane = tid & 63;
    const int blk  = blockIdx.x;
    const int gb   = blk & 63;        // batch group
    const int hg   = blk >> 6;        // hcol quarter 0..3

    const int gate = w & 3;
    const int ntl0 = (w >> 2) * 2;    // local h-ntile pair base (0 or 2)

    const int m_x = tid >> 4;         // x-gather row (tid<256)
    const int e_x = tid & 15;

    const int r_gm = tid >> 5;        // gate-math row 0..15
    const int hc0  = (tid * 2) & 63;  // gate-math col pair base (even)

    const int myq    = (tid & 31) >> 3;   // producer quarter this thread stages
    const bool remote = (myq != hg);

    const i32x4* Bg = (const i32x4*)wswz;

    // --- B prologue: regs for kits {0,1,2,3,4,7,8} (56 VGPRs) ---
    i32x4 breg[7][2];
    {
        const int ks[7] = {0, 1, 2, 3, 4, 7, 8};
#pragma unroll
        for (int i = 0; i < 7; i++)
#pragma unroll
            for (int jj = 0; jj < 2; jj++) {
                int ntile = gate * 16 + hg * 4 + ntl0 + jj;
                breg[i][jj] = Bg[(ks[i] * 64 + ntile) * 64 + lane];
            }
    }
    // --- B LDS: kits 5,6 for this block's 16 ntiles ---
    for (int i = tid; i < 2 * 16 * 64; i += 512) {
        int k   = i >> 10;          // 0->kit5, 1->kit6
        int ntl = (i >> 6) & 15;    // local ntile = gt*4 + j
        int ln  = i & 63;
        int gt = ntl >> 2, j = ntl & 3;
        B_lds[i] = Bg[((5 + k) * 64 + gt * 16 + hg * 4 + j) * 64 + ln];
    }

    // --- A8 init: zeros, bias (both parities), x_0 (parity 0) ---
    {
        int4 z4 = {0, 0, 0, 0};
        if (tid < 128) ((int4*)A8_lds)[tid] = z4;
    }
    __syncthreads();
    if (tid < 16) {
        A8_lds[0][(16 + tid) * 8 + 2] = 0x3F80;  // bias=1.0 at k-local=10
        A8_lds[1][(16 + tid) * 8 + 2] = 0x3F80;
    }
    if (tid < 256 && e_x < EMBD) {
        int tok = xtok[(gb * 16 + m_x) * T_STEPS + 0];
        float v = emb[tok * EMBD + e_x];
        A8_lds[0][(m_x + 16 * (e_x >> 3)) * 8 + (e_x & 7)] = f2bf(v);
    }
    __syncthreads();

    float c0 = 0.0f, c1 = 0.0f;

    // af LDS read base (i32x4 units): row (lane&15) * 33 + quad; af[s] at +4s
    const int ah_rd = (lane & 15) * 33 + (lane >> 4);
    // staging write slot (i32x4 units): logical row (tid>>5), col (tid&31)
    const int ah_wr = (tid >> 5) * 33 + (tid & 31);

    for (int t = 0; t < T_STEPS; t++) {
        const int p = t & 1, q = (t + 1) & 1;

        // x(t+1) prefetch (independent)
        float xval = 0.0f;
        const bool do_x = (t < T_STEPS - 1) && (tid < 256) && (e_x < EMBD);
        if ((t < T_STEPS - 1) && (tid < 256)) {
            int tok = xtok[(gb * 16 + m_x) * T_STEPS + (t + 1)];
            if (e_x < EMBD) xval = emb[tok * EMBD + e_x];
        }

        // distributed poll + stage ISSUE (remote-quarter threads only)
        i32x4 hstage;
        if (t > 0) {
            if (remote) {
                const unsigned int* fp = &flags[(p * 64 + gb) * 4 + myq];
                int spins = 0;
                for (;;) {
                    unsigned int fv;
                    asm volatile("global_load_dword %0, %1, off sc1\n\t"
                                 "s_waitcnt vmcnt(0)"
                                 : "=v"(fv) : "v"(fp) : "memory");
                    if ((int)(fv - (unsigned)t) >= 0) break;
                    __builtin_amdgcn_s_sleep(1);
                    if (++spins > 400000) break;  // hang-proof
                }
                const unsigned int* sp = hxc + (size_t)(p * 64 + gb) * 2048 + tid * 4;
                asm volatile("global_load_dwordx4 %0, %1, off sc1"
                             : "=&v"(hstage) : "v"(sp) : "memory");
            }
        }

        f32x4 acc0 = (f32x4){0.f, 0.f, 0.f, 0.f};
        f32x4 acc1 = (f32x4){0.f, 0.f, 0.f, 0.f};
        // kit 8 (x + bias; h-independent) overlaps the in-flight stage loads
        {
            i32x4 a8 = ((const i32x4*)A8_lds[p])[lane];
            acc0 = mfma_v(a8, breg[6][0], acc0);
            acc1 = mfma_v(a8, breg[6][1], acc1);
        }

        // land staged h into LDS (rule-18 fence), then read af fragments
        i32x4 af[8];
        if (t > 0) {
            if (remote) {
                asm volatile("s_waitcnt vmcnt(0)" ::: "memory");
                __builtin_amdgcn_sched_barrier(0);
                ((i32x4*)Ah_lds)[ah_wr] = hstage;
            }
            __syncthreads();   // remote quarters landed; own quarter written last tail
#pragma unroll
            for (int s = 0; s < 8; s++)
                af[s] = ((const i32x4*)Ah_lds)[ah_rd + s * 4];
        } else {
#pragma unroll
            for (int s = 0; s < 8; s++) af[s] = (i32x4){0, 0, 0, 0};
        }

        // kits 0,1,2,3,4,7 (B in regs)
        {
            const int ks6[6] = {0, 1, 2, 3, 4, 7};
#pragma unroll
            for (int i = 0; i < 6; i++) {
                acc0 = mfma_v(af[ks6[i]], breg[i][0], acc0);
                acc1 = mfma_v(af[ks6[i]], breg[i][1], acc1);
            }
        }
        // kits 5,6 (B in LDS)
#pragma unroll
        for (int k = 0; k < 2; k++) {
            acc0 = mfma_v(af[5 + k], B_lds[(k * 16 + gate * 4 + ntl0 + 0) * 64 + lane], acc0);
            acc1 = mfma_v(af[5 + k], B_lds[(k * 16 + gate * 4 + ntl0 + 1) * 64 + lane], acc1);
        }

        // z -> z_lds (C layout: batch row m = (lane>>4)*4+reg, ncol = lane&15)
        {
            const int col = lane & 15, qd = lane >> 4;
#pragma unroll
            for (int rr = 0; rr < 4; rr++) {
                z_lds[(gate * 16 + qd * 4 + rr) * 66 + (ntl0 + 0) * 16 + col] = acc0[rr];
                z_lds[(gate * 16 + qd * 4 + rr) * 66 + (ntl0 + 1) * 16 + col] = acc1[rr];
            }
        }
        __syncthreads();  // B1: z complete (af reads also retired)

        // gate math: 2 h-values per thread (row r_gm, hcols hc0/hc0+1)
        float zg[4], zh[4];
#pragma unroll
        for (int g = 0; g < 4; g++) {
            const float2 zz = *(const float2*)&z_lds[(g * 16 + r_gm) * 66 + hc0];
            zg[g] = zz.x; zh[g] = zz.y;
        }
        float hh0, hh1;
        {
            float gg = tanh_fast(zg[0]), ii = sig_fast(zg[1]);
            float ff = sig_fast(zg[2]),  oo = sig_fast(zg[3]);
            float cn = gg * ii + c0 * ff; c0 = cn;
            hh0 = tanh_fast(cn) * oo;
        }
        {
            float gg = tanh_fast(zh[0]), ii = sig_fast(zh[1]);
            float ff = sig_fast(zh[2]),  oo = sig_fast(zh[3]);
            float cn = gg * ii + c1 * ff; c1 = cn;
            hh1 = tanh_fast(cn) * oo;
        }

        if (t < T_STEPS - 1) {
            unsigned int hp;
            asm("v_cvt_pk_bf16_f32 %0, %1, %2" : "=v"(hp) : "v"(hh0), "v"(hh1));
            // remote consumers read from hxc (sc1 write-through to LLC)
            __hip_atomic_store(
                &hxc[(size_t)(q * 64 + gb) * 2048 + r_gm * 128 + ((hg * 64 + hc0) >> 1)],
                hp, __ATOMIC_RELAXED, __HIP_MEMORY_SCOPE_AGENT);
            // own quarter goes straight to LDS for our own next step
            Ah_lds[r_gm * 132 + hg * 32 + (hc0 >> 1)] = hp;
            if (do_x)
                A8_lds[q][(m_x + 16 * (e_x >> 3)) * 8 + (e_x & 7)] = f2bf(xval);
            __syncthreads();  // B2: drains vmcnt -> h stores acked at LLC
            if (tid == 0)
                __hip_atomic_store(&flags[(q * 64 + gb) * 4 + hg], (unsigned)(t + 1),
                                   __ATOMIC_RELAXED, __HIP_MEMORY_SCOPE_AGENT);
        } else {
            // --- epilogue: project final h (held in hh0/hh1) ---
            if (tid < 160) outacc[tid] = 0.0f;
            __syncthreads();
            const int hcg = hg * 64 + hc0;
            float part[10];
#pragma unroll
            for (int cl = 0; cl < 10; cl++)
                part[cl] = hh0 * Wph[hcg * 10 + cl] + hh1 * Wph[(hcg + 1) * 10 + cl];
#pragma unroll
            for (int cl = 0; cl < 10; cl++)
                atomicAdd(&outacc[r_gm * 10 + cl], part[cl]);
            __syncthreads();
            if (tid < 160) {
                int m = tid / 10, cl = tid - m * 10;
                float v = outacc[tid];
                if (hg == 0) v += bp[cl];     // bias added exactly once per row
                atomicAdd(&out[(gb * 16 + m) * 10 + cl], v);
            }
        }
    }
}

extern "C" void kernel_launch(void* const* d_in, const int* in_sizes, int n_in,
                              void* d_out, int out_size, void* d_ws, size_t ws_size,
                              hipStream_t stream) {
    const int*   x    = (const int*)  d_in[0];
    const float* emb  = (const float*)d_in[1];
    const float* Wgx  = (const float*)d_in[2];
    const float* Wgh  = (const float*)d_in[3];
    const float* bg   = (const float*)d_in[4];
    const float* Wix  = (const float*)d_in[5];
    const float* Wih  = (const float*)d_in[6];
    const float* bi   = (const float*)d_in[7];
    const float* Wfx  = (const float*)d_in[8];
    const float* Wfh  = (const float*)d_in[9];
    const float* bf_  = (const float*)d_in[10];
    const float* Wox  = (const float*)d_in[11];
    const float* Woh  = (const float*)d_in[12];
    const float* bo   = (const float*)d_in[13];
    const float* Wph  = (const float*)d_in[14];
    const float* bp   = (const float*)d_in[15];

    char* ws = (char*)d_ws;
    unsigned short* wswz  = (unsigned short*)ws;                    // 576 KB
    unsigned int*   flags = (unsigned int*)(ws + 589824);           // 2 KB (4K pad)
    unsigned int*   hxc   = (unsigned int*)(ws + 589824 + 4096);    // 1 MB

    build_wswz<<<NBLK_K1, 64, 0, stream>>>(Wgx, Wgh, bg, Wix, Wih, bi,
                                           Wfx, Wfh, bf_, Wox, Woh, bo,
                                           wswz, flags);
    lstm_main<<<NBLK, 512, 0, stream>>>(x, emb, Wph, bp, wswz, flags, hxc,
                                        (float*)d_out);
}

// Round 13
// 585.300 us; speedup vs baseline: 3.5493x; 1.1564x over previous
//
#include <hip/hip_runtime.h>
#include <stdint.h>

#define T_STEPS 256
#define EMBD 10
#define NKIT 9          // K = 288 = 9*32 (256 h + 10 x + 1 bias + pad)
#define NBLK_K1 (64 * NKIT)
#define NBLK 256        // main grid: 4 hcol-quarters x 64 batch-groups

typedef __attribute__((ext_vector_type(8))) short bf16x8;
typedef __attribute__((ext_vector_type(4))) float f32x4;
typedef __attribute__((ext_vector_type(4))) int   i32x4;

__device__ __forceinline__ unsigned short f2bf(float f) {
    union { float f; unsigned int u; } v; v.f = f;
    unsigned int u = v.u;
    unsigned int r = (u + 0x7FFFu + ((u >> 16) & 1u)) >> 16;  // RNE
    return (unsigned short)r;
}
__device__ __forceinline__ float sig_fast(float x) {
    return __builtin_amdgcn_rcpf(1.0f + __builtin_amdgcn_exp2f(-1.4426950408889634f * x));
}
__device__ __forceinline__ float tanh_fast(float x) {
    return 1.0f - 2.0f * __builtin_amdgcn_rcpf(__builtin_amdgcn_exp2f(2.8853900817779268f * x) + 1.0f);
}
__device__ __forceinline__ f32x4 mfma_v(i32x4 a, i32x4 b, f32x4 c) {
    return __builtin_amdgcn_mfma_f32_16x16x32_bf16(
        __builtin_bit_cast(bf16x8, a), __builtin_bit_cast(bf16x8, b), c, 0, 0, 0);
}

// ---------------------------------------------------------------------------
// K1: swizzled bf16 weights [kit][ntile][lane] x 16B. All blocks also zero
// the 2 MB hxc region (seq words must start != any expected step; zero works
// since expected seq >= 1). R23 lesson: spread the zeroing across the grid.
// ---------------------------------------------------------------------------
__global__ __launch_bounds__(64) void build_wswz(
    const float* __restrict__ Wgx, const float* __restrict__ Wgh, const float* __restrict__ bg,
    const float* __restrict__ Wix, const float* __restrict__ Wih, const float* __restrict__ bi,
    const float* __restrict__ Wfx, const float* __restrict__ Wfh, const float* __restrict__ bf_,
    const float* __restrict__ Wox, const float* __restrict__ Woh, const float* __restrict__ bo,
    unsigned short* __restrict__ wswz, unsigned int* __restrict__ hxcz)
{
    // zero hxc: 2 MB = 131072 int4 across 576*64 threads (~4 iters)
    {
        int4 z4 = {0, 0, 0, 0};
        size_t gid = (size_t)blockIdx.x * 64 + threadIdx.x;
        for (size_t i = gid; i < 131072; i += (size_t)NBLK_K1 * 64)
            ((int4*)hxcz)[i] = z4;
    }

    int g   = blockIdx.x / NKIT;   // ntile
    int kit = blockIdx.x % NKIT;
    int lane = threadIdx.x;
    int n = g * 16 + (lane & 15);
    int q = n >> 8;
    int col = n & 255;
    const float* Wh = (q == 0) ? Wgh : (q == 1) ? Wih : (q == 2) ? Wfh : Woh;
    const float* Wx = (q == 0) ? Wgx : (q == 1) ? Wix : (q == 2) ? Wfx : Wox;
    const float* bb = (q == 0) ? bg  : (q == 1) ? bi  : (q == 2) ? bf_ : bo;
    int k0 = kit * 32 + (lane >> 4) * 8;

    int4 out;
    unsigned short* p = (unsigned short*)&out;
#pragma unroll
    for (int jx = 0; jx < 8; jx++) {
        int k = k0 + jx;
        float v = 0.0f;
        if (k < 256)             v = Wh[k * 256 + col];
        else if (k < 256 + EMBD) v = Wx[(k - 256) * 256 + col];
        else if (k == 266)       v = bb[col];
        p[jx] = f2bf(v);
    }
    ((int4*)wswz)[(kit * 64 + g) * 64 + lane] = out;
}

// ---------------------------------------------------------------------------
// K2: N-SPLIT persistent LSTM. R30: SELF-VALIDATING h exchange -- no flags,
// no drain-before-post, no poll RT. hxc entries are u64 {hi: seq, lo: 2xbf16}
// (8B-aligned stores are single-copy atomic). Producer at end of step t
// fire-and-forgets its pairs with seq=t+1 (after the tail LDS writes, so no
// barrier ever drains them). Consumer at step t loads its 3 remote-quarter
// u64s and RETRIES until seq==t (bounded; per-thread; absorbs skew).
// Serial chain/step: ~1 overlapped stage RT + 2 barriers + compute
// (was: drain RT + flag RT + stage RT + 3 barriers).
// WAR without flags (audited): producer reaches its t+2 write only after
// staging all siblings' t+1 (seq-validated), which exists only after those
// siblings completed their t reads -> parity double-buffer slot is free.
// Buffers single-Ah: stage(t) writes happen after B1(t-1) (barrier) and
// af(t-1) reads happen before B1(t-1) -> no race.
// ---------------------------------------------------------------------------
__global__ __launch_bounds__(512, 4)
void lstm_main(
    const int*   __restrict__ xtok,   // [1024][1][256]
    const float* __restrict__ emb,    // [32000][10]
    const float* __restrict__ Wph,    // [256][10]
    const float* __restrict__ bp,     // [10]
    const unsigned short* __restrict__ wswz,
    unsigned long long* __restrict__ hxc,  // [2][64][16][128] u64 {seq, 2xbf16}
    float* __restrict__ out)          // [1024][10]
{
    __shared__ __align__(16) unsigned short A8_lds[2][64 * 8];  // 2 KB (kit 8: x+bias)
    __shared__ __align__(16) i32x4 B_lds[2 * 16 * 64];          // 32 KB (kits 5,6)
    __shared__ __align__(16) unsigned int Ah_lds[16 * 132];     // 8.25 KB (h, padded)
    __shared__ float z_lds[4 * 16 * 66];                        // 16.5 KB (padded 66)
    __shared__ float outacc[160];

    const int tid  = threadIdx.x;
    const int w    = tid >> 6;        // wave 0..7
    const int lane = tid & 63;
    const int blk  = blockIdx.x;
    const int gb   = blk & 63;        // batch group
    const int hg   = blk >> 6;        // hcol quarter 0..3

    const int gate = w & 3;
    const int ntl0 = (w >> 2) * 2;    // local h-ntile pair base (0 or 2)

    const int m_x = tid >> 4;         // x-gather row (tid<256)
    const int e_x = tid & 15;

    const int r_gm = tid >> 5;        // gate-math row 0..15
    const int hc0  = (tid * 2) & 63;  // gate-math col pair base (even)

    const i32x4* Bg = (const i32x4*)wswz;

    // --- B prologue: regs for kits {0,1,2,3,4,7,8} (56 VGPRs) ---
    i32x4 breg[7][2];
    {
        const int ks[7] = {0, 1, 2, 3, 4, 7, 8};
#pragma unroll
        for (int i = 0; i < 7; i++)
#pragma unroll
            for (int jj = 0; jj < 2; jj++) {
                int ntile = gate * 16 + hg * 4 + ntl0 + jj;
                breg[i][jj] = Bg[(ks[i] * 64 + ntile) * 64 + lane];
            }
    }
    // --- B LDS: kits 5,6 for this block's 16 ntiles ---
    for (int i = tid; i < 2 * 16 * 64; i += 512) {
        int k   = i >> 10;          // 0->kit5, 1->kit6
        int ntl = (i >> 6) & 15;    // local ntile = gt*4 + j
        int ln  = i & 63;
        int gt = ntl >> 2, j = ntl & 3;
        B_lds[i] = Bg[((5 + k) * 64 + gt * 16 + hg * 4 + j) * 64 + ln];
    }

    // --- A8 init: zeros, bias (both parities), x_0 (parity 0) ---
    {
        int4 z4 = {0, 0, 0, 0};
        if (tid < 128) ((int4*)A8_lds)[tid] = z4;
    }
    __syncthreads();
    if (tid < 16) {
        A8_lds[0][(16 + tid) * 8 + 2] = 0x3F80;  // bias=1.0 at k-local=10
        A8_lds[1][(16 + tid) * 8 + 2] = 0x3F80;
    }
    if (tid < 256 && e_x < EMBD) {
        int tok = xtok[(gb * 16 + m_x) * T_STEPS + 0];
        float v = emb[tok * EMBD + e_x];
        A8_lds[0][(m_x + 16 * (e_x >> 3)) * 8 + (e_x & 7)] = f2bf(v);
    }
    __syncthreads();

    float c0 = 0.0f, c1 = 0.0f;

    // af LDS read base (i32x4 units): row (lane&15) * 33 + quad; af[s] at +4s
    const int ah_rd = (lane & 15) * 33 + (lane >> 4);
    // per-thread slot: row (tid>>5), pair (tid&31)
    const int s_row  = tid >> 5;
    const int s_pair = tid & 31;
    const int rq0 = (hg + 1) & 3, rq1 = (hg + 2) & 3, rq2 = (hg + 3) & 3;

    for (int t = 0; t < T_STEPS; t++) {
        const int p = t & 1, q = (t + 1) & 1;

        // x(t+1) prefetch (independent)
        float xval = 0.0f;
        const bool do_x = (t < T_STEPS - 1) && (tid < 256) && (e_x < EMBD);
        if ((t < T_STEPS - 1) && (tid < 256)) {
            int tok = xtok[(gb * 16 + m_x) * T_STEPS + (t + 1)];
            if (e_x < EMBD) xval = emb[tok * EMBD + e_x];
        }

        // stage remote h(t): 3 seq-tagged u64 loads, retry-until-valid
        if (t > 0) {
            const unsigned long long* hb = hxc + (size_t)(p * 64 + gb) * 2048;
            const unsigned long long* a0 = hb + s_row * 128 + rq0 * 32 + s_pair;
            const unsigned long long* a1 = hb + s_row * 128 + rq1 * 32 + s_pair;
            const unsigned long long* a2 = hb + s_row * 128 + rq2 * 32 + s_pair;
            unsigned long long v0, v1, v2;
            // all 3 in one asm block: overlapped RTs, waitcnt same-block (safe)
            asm volatile("global_load_dwordx2 %0, %3, off sc1\n\t"
                         "global_load_dwordx2 %1, %4, off sc1\n\t"
                         "global_load_dwordx2 %2, %5, off sc1\n\t"
                         "s_waitcnt vmcnt(0)"
                         : "=&v"(v0), "=&v"(v1), "=&v"(v2)
                         : "v"(a0), "v"(a1), "v"(a2) : "memory");
            int spins = 0;
            while ((unsigned int)(v0 >> 32) != (unsigned int)t && spins < 200000) {
                __builtin_amdgcn_s_sleep(1); ++spins;
                asm volatile("global_load_dwordx2 %0, %1, off sc1\n\ts_waitcnt vmcnt(0)"
                             : "=v"(v0) : "v"(a0) : "memory");
            }
            while ((unsigned int)(v1 >> 32) != (unsigned int)t && spins < 200000) {
                __builtin_amdgcn_s_sleep(1); ++spins;
                asm volatile("global_load_dwordx2 %0, %1, off sc1\n\ts_waitcnt vmcnt(0)"
                             : "=v"(v1) : "v"(a1) : "memory");
            }
            while ((unsigned int)(v2 >> 32) != (unsigned int)t && spins < 200000) {
                __builtin_amdgcn_s_sleep(1); ++spins;
                asm volatile("global_load_dwordx2 %0, %1, off sc1\n\ts_waitcnt vmcnt(0)"
                             : "=v"(v2) : "v"(a2) : "memory");
            }
            Ah_lds[s_row * 132 + rq0 * 32 + s_pair] = (unsigned int)v0;
            Ah_lds[s_row * 132 + rq1 * 32 + s_pair] = (unsigned int)v1;
            Ah_lds[s_row * 132 + rq2 * 32 + s_pair] = (unsigned int)v2;
        }
        __syncthreads();  // LAND: staged + own-tail + A8 writes visible

        // af fragments from LDS (t=0: zeros)
        i32x4 af[8];
        if (t > 0) {
#pragma unroll
            for (int s = 0; s < 8; s++)
                af[s] = ((const i32x4*)Ah_lds)[ah_rd + s * 4];
        } else {
#pragma unroll
            for (int s = 0; s < 8; s++) af[s] = (i32x4){0, 0, 0, 0};
        }

        f32x4 acc0 = (f32x4){0.f, 0.f, 0.f, 0.f};
        f32x4 acc1 = (f32x4){0.f, 0.f, 0.f, 0.f};
        // kit 8 (x + bias)
        {
            i32x4 a8 = ((const i32x4*)A8_lds[p])[lane];
            acc0 = mfma_v(a8, breg[6][0], acc0);
            acc1 = mfma_v(a8, breg[6][1], acc1);
        }
        // kits 0,1,2,3,4,7 (B in regs)
        {
            const int ks6[6] = {0, 1, 2, 3, 4, 7};
#pragma unroll
            for (int i = 0; i < 6; i++) {
                acc0 = mfma_v(af[ks6[i]], breg[i][0], acc0);
                acc1 = mfma_v(af[ks6[i]], breg[i][1], acc1);
            }
        }
        // kits 5,6 (B in LDS)
#pragma unroll
        for (int k = 0; k < 2; k++) {
            acc0 = mfma_v(af[5 + k], B_lds[(k * 16 + gate * 4 + ntl0 + 0) * 64 + lane], acc0);
            acc1 = mfma_v(af[5 + k], B_lds[(k * 16 + gate * 4 + ntl0 + 1) * 64 + lane], acc1);
        }

        // z -> z_lds (C layout: batch row m = (lane>>4)*4+reg, ncol = lane&15)
        {
            const int col = lane & 15, qd = lane >> 4;
#pragma unroll
            for (int rr = 0; rr < 4; rr++) {
                z_lds[(gate * 16 + qd * 4 + rr) * 66 + (ntl0 + 0) * 16 + col] = acc0[rr];
                z_lds[(gate * 16 + qd * 4 + rr) * 66 + (ntl0 + 1) * 16 + col] = acc1[rr];
            }
        }
        __syncthreads();  // B1: z complete (af reads also retired)

        // gate math: 2 h-values per thread (row r_gm, hcols hc0/hc0+1)
        float zg[4], zh[4];
#pragma unroll
        for (int g = 0; g < 4; g++) {
            const float2 zz = *(const float2*)&z_lds[(g * 16 + r_gm) * 66 + hc0];
            zg[g] = zz.x; zh[g] = zz.y;
        }
        float hh0, hh1;
        {
            float gg = tanh_fast(zg[0]), ii = sig_fast(zg[1]);
            float ff = sig_fast(zg[2]),  oo = sig_fast(zg[3]);
            float cn = gg * ii + c0 * ff; c0 = cn;
            hh0 = tanh_fast(cn) * oo;
        }
        {
            float gg = tanh_fast(zh[0]), ii = sig_fast(zh[1]);
            float ff = sig_fast(zh[2]),  oo = sig_fast(zh[3]);
            float cn = gg * ii + c1 * ff; c1 = cn;
            hh1 = tanh_fast(cn) * oo;
        }

        if (t < T_STEPS - 1) {
            unsigned int hp;
            asm("v_cvt_pk_bf16_f32 %0, %1, %2" : "=v"(hp) : "v"(hh0), "v"(hh1));
            // own quarter straight to LDS (consumed by us after next LAND)
            Ah_lds[r_gm * 132 + hg * 32 + (hc0 >> 1)] = hp;
            if (do_x)
                A8_lds[q][(m_x + 16 * (e_x >> 3)) * 8 + (e_x & 7)] = f2bf(xval);
            // fire-and-forget seq-tagged u64 (NO drain, NO flag):
            unsigned long long pv =
                ((unsigned long long)(unsigned int)(t + 1) << 32) | (unsigned long long)hp;
            unsigned long long* dst =
                hxc + (size_t)(q * 64 + gb) * 2048 + r_gm * 128 + hg * 32 + (hc0 >> 1);
            asm volatile("global_store_dwordx2 %0, %1, off sc1"
                         :: "v"(dst), "v"(pv) : "memory");
        } else {
            // --- epilogue: project final h (held in hh0/hh1) ---
            if (tid < 160) outacc[tid] = 0.0f;
            __syncthreads();
            const int hcg = hg * 64 + hc0;
            float part[10];
#pragma unroll
            for (int cl = 0; cl < 10; cl++)
                part[cl] = hh0 * Wph[hcg * 10 + cl] + hh1 * Wph[(hcg + 1) * 10 + cl];
#pragma unroll
            for (int cl = 0; cl < 10; cl++)
                atomicAdd(&outacc[r_gm * 10 + cl], part[cl]);
            __syncthreads();
            if (tid < 160) {
                int m = tid / 10, cl = tid - m * 10;
                float v = outacc[tid];
                if (hg == 0) v += bp[cl];     // bias added exactly once per row
                atomicAdd(&out[(gb * 16 + m) * 10 + cl], v);
            }
        }
    }
}

extern "C" void kernel_launch(void* const* d_in, const int* in_sizes, int n_in,
                              void* d_out, int out_size, void* d_ws, size_t ws_size,
                              hipStream_t stream) {
    const int*   x    = (const int*)  d_in[0];
    const float* emb  = (const float*)d_in[1];
    const float* Wgx  = (const float*)d_in[2];
    const float* Wgh  = (const float*)d_in[3];
    const float* bg   = (const float*)d_in[4];
    const float* Wix  = (const float*)d_in[5];
    const float* Wih  = (const float*)d_in[6];
    const float* bi   = (const float*)d_in[7];
    const float* Wfx  = (const float*)d_in[8];
    const float* Wfh  = (const float*)d_in[9];
    const float* bf_  = (const float*)d_in[10];
    const float* Wox  = (const float*)d_in[11];
    const float* Woh  = (const float*)d_in[12];
    const float* bo   = (const float*)d_in[13];
    const float* Wph  = (const float*)d_in[14];
    const float* bp   = (const float*)d_in[15];

    char* ws = (char*)d_ws;
    unsigned short*     wswz = (unsigned short*)ws;                 // 576 KB
    unsigned long long* hxc  = (unsigned long long*)(ws + 589824 + 4096); // 2 MB

    build_wswz<<<NBLK_K1, 64, 0, stream>>>(Wgx, Wgh, bg, Wix, Wih, bi,
                                           Wfx, Wfh, bf_, Wox, Woh, bo,
                                           wswz, (unsigned int*)hxc);
    lstm_main<<<NBLK, 512, 0, stream>>>(x, emb, Wph, bp, wswz, hxc,
                                        (float*)d_out);
}

// Round 14
// 532.227 us; speedup vs baseline: 3.9033x; 1.0997x over previous
//
#include <hip/hip_runtime.h>
#include <stdint.h>

#define T_STEPS 256
#define EMBD 10
#define NKIT 9          // K = 288 = 9*32 (256 h + 10 x + 1 bias + pad)
#define NBLK_K1 (64 * NKIT)
#define NBLK 256        // main grid: 4 hcol-quarters x 64 batch-groups

typedef __attribute__((ext_vector_type(8))) short bf16x8;
typedef __attribute__((ext_vector_type(4))) float f32x4;
typedef __attribute__((ext_vector_type(4))) int   i32x4;

__device__ __forceinline__ unsigned short f2bf(float f) {
    union { float f; unsigned int u; } v; v.f = f;
    unsigned int u = v.u;
    unsigned int r = (u + 0x7FFFu + ((u >> 16) & 1u)) >> 16;  // RNE
    return (unsigned short)r;
}
__device__ __forceinline__ float sig_fast(float x) {
    return __builtin_amdgcn_rcpf(1.0f + __builtin_amdgcn_exp2f(-1.4426950408889634f * x));
}
__device__ __forceinline__ float tanh_fast(float x) {
    return 1.0f - 2.0f * __builtin_amdgcn_rcpf(__builtin_amdgcn_exp2f(2.8853900817779268f * x) + 1.0f);
}
__device__ __forceinline__ f32x4 mfma_v(i32x4 a, i32x4 b, f32x4 c) {
    return __builtin_amdgcn_mfma_f32_16x16x32_bf16(
        __builtin_bit_cast(bf16x8, a), __builtin_bit_cast(bf16x8, b), c, 0, 0, 0);
}

// ---------------------------------------------------------------------------
// K1: swizzled bf16 weights [kit][ntile][lane] x 16B + zero the 2 MB hxc
// (seq words must start != any expected step; zero works, expected >= 1).
// ---------------------------------------------------------------------------
__global__ __launch_bounds__(64) void build_wswz(
    const float* __restrict__ Wgx, const float* __restrict__ Wgh, const float* __restrict__ bg,
    const float* __restrict__ Wix, const float* __restrict__ Wih, const float* __restrict__ bi,
    const float* __restrict__ Wfx, const float* __restrict__ Wfh, const float* __restrict__ bf_,
    const float* __restrict__ Wox, const float* __restrict__ Woh, const float* __restrict__ bo,
    unsigned short* __restrict__ wswz, unsigned int* __restrict__ hxcz)
{
    {
        int4 z4 = {0, 0, 0, 0};
        size_t gid = (size_t)blockIdx.x * 64 + threadIdx.x;
        for (size_t i = gid; i < 131072; i += (size_t)NBLK_K1 * 64)
            ((int4*)hxcz)[i] = z4;
    }

    int g   = blockIdx.x / NKIT;   // ntile
    int kit = blockIdx.x % NKIT;
    int lane = threadIdx.x;
    int n = g * 16 + (lane & 15);
    int q = n >> 8;
    int col = n & 255;
    const float* Wh = (q == 0) ? Wgh : (q == 1) ? Wih : (q == 2) ? Wfh : Woh;
    const float* Wx = (q == 0) ? Wgx : (q == 1) ? Wix : (q == 2) ? Wfx : Wox;
    const float* bb = (q == 0) ? bg  : (q == 1) ? bi  : (q == 2) ? bf_ : bo;
    int k0 = kit * 32 + (lane >> 4) * 8;

    int4 out;
    unsigned short* p = (unsigned short*)&out;
#pragma unroll
    for (int jx = 0; jx < 8; jx++) {
        int k = k0 + jx;
        float v = 0.0f;
        if (k < 256)             v = Wh[k * 256 + col];
        else if (k < 256 + EMBD) v = Wx[(k - 256) * 256 + col];
        else if (k == 266)       v = bb[col];
        p[jx] = f2bf(v);
    }
    ((int4*)wswz)[(kit * 64 + g) * 64 + lane] = out;
}

// kit -> B source helpers (all compile-time s; rule 20: no runtime indexing)
#define KIDX(s) ((s) == 7 ? 5 : (s))
#define BSRC(s, j) ((s) == 5 ? B_lds[(0 * 16 + gate * 4 + ntl0 + (j)) * 64 + lane] \
                  : (s) == 6 ? B_lds[(1 * 16 + gate * 4 + ntl0 + (j)) * 64 + lane] \
                  : breg[KIDX(s)][(j)])
#define DO_KIT(s) do { i32x4 a_ = ((const i32x4*)Ah_lds)[ah_rd + (s) * 4]; \
        acc0 = mfma_v(a_, BSRC(s, 0), acc0); \
        acc1 = mfma_v(a_, BSRC(s, 1), acc1); } while (0)

// ---------------------------------------------------------------------------
// K2: N-SPLIT persistent LSTM, R30 self-validating u64 exchange (verified:
// {hi:seq, lo:2xbf16}, fire-and-forget stores, retry-until-seq==t, WAR safe
// by the recurrence itself). R31 fixes R30's measured gap (527us vs ~340
// modeled): R30's THREE SEQUENTIAL retry loops serialized ~3x700cyc of LLC
// RT when all quarters were stale (the common case).
//  (1) COMBINED retry: reload all 3 quarters in ONE asm block per iteration
//      (overlapped RTs) -> 1 RT instead of 3.
//  (2) Compute under the RT: issue remote loads at step top (no wait),
//      cross a RAW s_barrier with lgkmcnt(0) ONLY (full __syncthreads would
//      drain vmcnt and kill the pipeline), compute kit8 + OWN-quarter kits
//      (h already in LDS from our own tail write), then validate via
//      s_waitcnt vmcnt(0) threaded through v0..v2 ("+v" dataflow, rule-18
//      safe), land remotes, raw barrier, remaining 6 kits.
//  (3) t=0 skips all h-kits (af==0 contributes nothing).
// ---------------------------------------------------------------------------
__global__ __launch_bounds__(512, 4)
void lstm_main(
    const int*   __restrict__ xtok,   // [1024][1][256]
    const float* __restrict__ emb,    // [32000][10]
    const float* __restrict__ Wph,    // [256][10]
    const float* __restrict__ bp,     // [10]
    const unsigned short* __restrict__ wswz,
    unsigned long long* __restrict__ hxc,  // [2][64][16][128] u64 {seq, 2xbf16}
    float* __restrict__ out)          // [1024][10]
{
    __shared__ __align__(16) unsigned short A8_lds[2][64 * 8];  // 2 KB (kit 8: x+bias)
    __shared__ __align__(16) i32x4 B_lds[2 * 16 * 64];          // 32 KB (kits 5,6)
    __shared__ __align__(16) unsigned int Ah_lds[16 * 132];     // 8.25 KB (h, padded)
    __shared__ float z_lds[4 * 16 * 66];                        // 16.5 KB (padded 66)
    __shared__ float outacc[160];

    const int tid  = threadIdx.x;
    const int w    = tid >> 6;        // wave 0..7
    const int lane = tid & 63;
    const int blk  = blockIdx.x;
    const int gb   = blk & 63;        // batch group
    const int hg   = blk >> 6;        // hcol quarter 0..3

    const int gate = w & 3;
    const int ntl0 = (w >> 2) * 2;    // local h-ntile pair base (0 or 2)

    const int m_x = tid >> 4;         // x-gather row (tid<256)
    const int e_x = tid & 15;

    const int r_gm = tid >> 5;        // gate-math row 0..15
    const int hc0  = (tid * 2) & 63;  // gate-math col pair base (even)

    const i32x4* Bg = (const i32x4*)wswz;

    // --- B prologue: regs for kits {0,1,2,3,4,7,8} (56 VGPRs) ---
    i32x4 breg[7][2];
    {
        const int ks[7] = {0, 1, 2, 3, 4, 7, 8};
#pragma unroll
        for (int i = 0; i < 7; i++)
#pragma unroll
            for (int jj = 0; jj < 2; jj++) {
                int ntile = gate * 16 + hg * 4 + ntl0 + jj;
                breg[i][jj] = Bg[(ks[i] * 64 + ntile) * 64 + lane];
            }
    }
    // --- B LDS: kits 5,6 for this block's 16 ntiles ---
    for (int i = tid; i < 2 * 16 * 64; i += 512) {
        int k   = i >> 10;          // 0->kit5, 1->kit6
        int ntl = (i >> 6) & 15;    // local ntile = gt*4 + j
        int ln  = i & 63;
        int gt = ntl >> 2, j = ntl & 3;
        B_lds[i] = Bg[((5 + k) * 64 + gt * 16 + hg * 4 + j) * 64 + ln];
    }

    // --- A8 init: zeros, bias (both parities), x_0 (parity 0) ---
    {
        int4 z4 = {0, 0, 0, 0};
        if (tid < 128) ((int4*)A8_lds)[tid] = z4;
    }
    __syncthreads();
    if (tid < 16) {
        A8_lds[0][(16 + tid) * 8 + 2] = 0x3F80;  // bias=1.0 at k-local=10
        A8_lds[1][(16 + tid) * 8 + 2] = 0x3F80;
    }
    if (tid < 256 && e_x < EMBD) {
        int tok = xtok[(gb * 16 + m_x) * T_STEPS + 0];
        float v = emb[tok * EMBD + e_x];
        A8_lds[0][(m_x + 16 * (e_x >> 3)) * 8 + (e_x & 7)] = f2bf(v);
    }
    __syncthreads();

    float c0 = 0.0f, c1 = 0.0f;

    // af LDS read base (i32x4 units): row (lane&15)*33 + quad; kit s at +4s
    const int ah_rd = (lane & 15) * 33 + (lane >> 4);
    // per-thread exchange slot: row (tid>>5), pair (tid&31)
    const int s_row  = tid >> 5;
    const int s_pair = tid & 31;
    const int rq0 = (hg + 1) & 3, rq1 = (hg + 2) & 3, rq2 = (hg + 3) & 3;

    for (int t = 0; t < T_STEPS; t++) {
        const int p = t & 1, q = (t + 1) & 1;

        // x(t+1) prefetch (independent)
        float xval = 0.0f;
        const bool do_x = (t < T_STEPS - 1) && (tid < 256) && (e_x < EMBD);
        if ((t < T_STEPS - 1) && (tid < 256)) {
            int tok = xtok[(gb * 16 + m_x) * T_STEPS + (t + 1)];
            if (e_x < EMBD) xval = emb[tok * EMBD + e_x];
        }

        const unsigned long long* hb = hxc + (size_t)(p * 64 + gb) * 2048;
        const unsigned long long* a0 = hb + s_row * 128 + rq0 * 32 + s_pair;
        const unsigned long long* a1 = hb + s_row * 128 + rq1 * 32 + s_pair;
        const unsigned long long* a2 = hb + s_row * 128 + rq2 * 32 + s_pair;
        unsigned long long v0 = 0, v1 = 0, v2 = 0;

        // ISSUE remote h(t) loads -- no wait, stays in flight across barrier
        if (t > 0) {
            asm volatile("global_load_dwordx2 %0, %3, off sc1\n\t"
                         "global_load_dwordx2 %1, %4, off sc1\n\t"
                         "global_load_dwordx2 %2, %5, off sc1"
                         : "=&v"(v0), "=&v"(v1), "=&v"(v2)
                         : "v"(a0), "v"(a1), "v"(a2) : "memory");
        }

        // LAND-own: raw barrier, LDS-only wait (keeps vmem in flight)
        asm volatile("s_waitcnt lgkmcnt(0)" ::: "memory");
        __builtin_amdgcn_s_barrier();

        f32x4 acc0 = (f32x4){0.f, 0.f, 0.f, 0.f};
        f32x4 acc1 = (f32x4){0.f, 0.f, 0.f, 0.f};
        // kit 8 (x + bias) -- h-independent
        {
            i32x4 a8 = ((const i32x4*)A8_lds[p])[lane];
            acc0 = mfma_v(a8, breg[6][0], acc0);
            acc1 = mfma_v(a8, breg[6][1], acc1);
        }

        if (t > 0) {
            // own-quarter kits (h in LDS from our own tail write) under the RT
            if      (hg == 0) { DO_KIT(0); DO_KIT(1); }
            else if (hg == 1) { DO_KIT(2); DO_KIT(3); }
            else if (hg == 2) { DO_KIT(4); DO_KIT(5); }
            else              { DO_KIT(6); DO_KIT(7); }

            // validate: wait threaded through v0..v2 (orders the reg reads)
            asm volatile("s_waitcnt vmcnt(0)"
                         : "+v"(v0), "+v"(v1), "+v"(v2) :: "memory");
            int spins = 0;
            while (((unsigned)(v0 >> 32) != (unsigned)t ||
                    (unsigned)(v1 >> 32) != (unsigned)t ||
                    (unsigned)(v2 >> 32) != (unsigned)t) && spins < 200000) {
                ++spins;
                __builtin_amdgcn_s_sleep(1);
                // reload ALL THREE in one block: overlapped RTs (R30 gap fix)
                asm volatile("global_load_dwordx2 %0, %3, off sc1\n\t"
                             "global_load_dwordx2 %1, %4, off sc1\n\t"
                             "global_load_dwordx2 %2, %5, off sc1\n\t"
                             "s_waitcnt vmcnt(0)"
                             : "=&v"(v0), "=&v"(v1), "=&v"(v2)
                             : "v"(a0), "v"(a1), "v"(a2) : "memory");
            }
            Ah_lds[s_row * 132 + rq0 * 32 + s_pair] = (unsigned int)v0;
            Ah_lds[s_row * 132 + rq1 * 32 + s_pair] = (unsigned int)v1;
            Ah_lds[s_row * 132 + rq2 * 32 + s_pair] = (unsigned int)v2;

            // LAND-remote: raw barrier, LDS-only wait
            asm volatile("s_waitcnt lgkmcnt(0)" ::: "memory");
            __builtin_amdgcn_s_barrier();

            // remaining 6 kits
            if (hg != 0) { DO_KIT(0); DO_KIT(1); }
            if (hg != 1) { DO_KIT(2); DO_KIT(3); }
            if (hg != 2) { DO_KIT(4); DO_KIT(5); }
            if (hg != 3) { DO_KIT(6); DO_KIT(7); }
        }

        // z -> z_lds (C layout: batch row m = (lane>>4)*4+reg, ncol = lane&15)
        {
            const int col = lane & 15, qd = lane >> 4;
#pragma unroll
            for (int rr = 0; rr < 4; rr++) {
                z_lds[(gate * 16 + qd * 4 + rr) * 66 + (ntl0 + 0) * 16 + col] = acc0[rr];
                z_lds[(gate * 16 + qd * 4 + rr) * 66 + (ntl0 + 1) * 16 + col] = acc1[rr];
            }
        }
        __syncthreads();  // B1: z complete (af reads also retired)

        // gate math: 2 h-values per thread (row r_gm, hcols hc0/hc0+1)
        float zg[4], zh[4];
#pragma unroll
        for (int g = 0; g < 4; g++) {
            const float2 zz = *(const float2*)&z_lds[(g * 16 + r_gm) * 66 + hc0];
            zg[g] = zz.x; zh[g] = zz.y;
        }
        float hh0, hh1;
        {
            float gg = tanh_fast(zg[0]), ii = sig_fast(zg[1]);
            float ff = sig_fast(zg[2]),  oo = sig_fast(zg[3]);
            float cn = gg * ii + c0 * ff; c0 = cn;
            hh0 = tanh_fast(cn) * oo;
        }
        {
            float gg = tanh_fast(zh[0]), ii = sig_fast(zh[1]);
            float ff = sig_fast(zh[2]),  oo = sig_fast(zh[3]);
            float cn = gg * ii + c1 * ff; c1 = cn;
            hh1 = tanh_fast(cn) * oo;
        }

        if (t < T_STEPS - 1) {
            unsigned int hp;
            asm("v_cvt_pk_bf16_f32 %0, %1, %2" : "=v"(hp) : "v"(hh0), "v"(hh1));
            // own quarter straight to LDS (consumed after next LAND-own)
            Ah_lds[r_gm * 132 + hg * 32 + (hc0 >> 1)] = hp;
            if (do_x)
                A8_lds[q][(m_x + 16 * (e_x >> 3)) * 8 + (e_x & 7)] = f2bf(xval);
            // fire-and-forget seq-tagged u64 (no drain, no flag)
            unsigned long long pv =
                ((unsigned long long)(unsigned int)(t + 1) << 32) | (unsigned long long)hp;
            unsigned long long* dst =
                hxc + (size_t)(q * 64 + gb) * 2048 + r_gm * 128 + hg * 32 + (hc0 >> 1);
            asm volatile("global_store_dwordx2 %0, %1, off sc1"
                         :: "v"(dst), "v"(pv) : "memory");
        } else {
            // --- epilogue: project final h (held in hh0/hh1) ---
            if (tid < 160) outacc[tid] = 0.0f;
            __syncthreads();
            const int hcg = hg * 64 + hc0;
            float part[10];
#pragma unroll
            for (int cl = 0; cl < 10; cl++)
                part[cl] = hh0 * Wph[hcg * 10 + cl] + hh1 * Wph[(hcg + 1) * 10 + cl];
#pragma unroll
            for (int cl = 0; cl < 10; cl++)
                atomicAdd(&outacc[r_gm * 10 + cl], part[cl]);
            __syncthreads();
            if (tid < 160) {
                int m = tid / 10, cl = tid - m * 10;
                float v = outacc[tid];
                if (hg == 0) v += bp[cl];     // bias added exactly once per row
                atomicAdd(&out[(gb * 16 + m) * 10 + cl], v);
            }
        }
    }
}

extern "C" void kernel_launch(void* const* d_in, const int* in_sizes, int n_in,
                              void* d_out, int out_size, void* d_ws, size_t ws_size,
                              hipStream_t stream) {
    const int*   x    = (const int*)  d_in[0];
    const float* emb  = (const float*)d_in[1];
    const float* Wgx  = (const float*)d_in[2];
    const float* Wgh  = (const float*)d_in[3];
    const float* bg   = (const float*)d_in[4];
    const float* Wix  = (const float*)d_in[5];
    const float* Wih  = (const float*)d_in[6];
    const float* bi   = (const float*)d_in[7];
    const float* Wfx  = (const float*)d_in[8];
    const float* Wfh  = (const float*)d_in[9];
    const float* bf_  = (const float*)d_in[10];
    const float* Wox  = (const float*)d_in[11];
    const float* Woh  = (const float*)d_in[12];
    const float* bo   = (const float*)d_in[13];
    const float* Wph  = (const float*)d_in[14];
    const float* bp   = (const float*)d_in[15];

    char* ws = (char*)d_ws;
    unsigned short*     wswz = (unsigned short*)ws;                 // 576 KB
    unsigned long long* hxc  = (unsigned long long*)(ws + 589824 + 4096); // 2 MB

    build_wswz<<<NBLK_K1, 64, 0, stream>>>(Wgx, Wgh, bg, Wix, Wih, bi,
                                           Wfx, Wfh, bf_, Wox, Woh, bo,
                                           wswz, (unsigned int*)hxc);
    lstm_main<<<NBLK, 512, 0, stream>>>(x, emb, Wph, bp, wswz, hxc,
                                        (float*)d_out);
}